// Round 17
// baseline (207.654 us; speedup 1.0000x reference)
//
#include <hip/hip_runtime.h>
#include <hip/hip_bf16.h>

typedef unsigned short u16;
typedef unsigned int   u32;
typedef unsigned long long u64;
typedef __attribute__((ext_vector_type(8))) short bf16x8;
typedef __attribute__((ext_vector_type(4))) float f32x4;
typedef __attribute__((ext_vector_type(16))) float f32x16;

#define MFMA16(a,b,c) __builtin_amdgcn_mfma_f32_16x16x32_bf16((a),(b),(c),0,0,0)
#define MFMA32(a,b,c) __builtin_amdgcn_mfma_f32_32x32x16_bf16((a),(b),(c),0,0,0)

#define GLD16(gp, lp) __builtin_amdgcn_global_load_lds( \
    (const __attribute__((address_space(1))) void*)(gp), \
    (__attribute__((address_space(3))) void*)(lp), 16, 0, 0)

__device__ inline u32 pkbf(float a, float b) {
  __hip_bfloat16 ha = __float2bfloat16(a), hb = __float2bfloat16(b);
  return (u32)(*(u16*)&ha) | ((u32)(*(u16*)&hb) << 16);
}
__device__ inline float b2f(u16 x) {
  __hip_bfloat16 h; *(u16*)&h = x; return __bfloat162float(h);
}
// fast bf16 pair pack: round (+0x8000) then byte-perm the two high halves
__device__ inline u32 pk2(float a, float b) {
  u32 ua = __builtin_bit_cast(u32, a) + 0x8000u;
  u32 ub = __builtin_bit_cast(u32, b) + 0x8000u;
  return __builtin_amdgcn_perm(ub, ua, 0x07060302u);
}
__device__ inline float fmax3(float a, float b, float c) {
  return fmaxf(fmaxf(a, b), c);
}

// ---------------------------------------------------------------- fused casts
__global__ __launch_bounds__(256) void cast_all(const float* __restrict__ x,
                                                const float* __restrict__ wq,
                                                const float* __restrict__ wk,
                                                const float* __restrict__ wv,
                                                const float* __restrict__ wo,
                                                u16* __restrict__ xb,
                                                u16* __restrict__ wqkv,
                                                u16* __restrict__ wob) {
  int i = blockIdx.x * 256 + threadIdx.x;
  const float* src; u16* dst; int off;
  if (i < 2097152)      { src = x;  dst = xb;                 off = 0; }
  else if (i < 3145728) { src = wq; dst = wqkv;               off = 2097152; }
  else if (i < 3407872) { src = wk; dst = wqkv + 4194304;     off = 3145728; }
  else if (i < 3670016) { src = wv; dst = wqkv + 5242880;     off = 3407872; }
  else                  { src = wo; dst = wob;                off = 3670016; }
  const int k = i - off;
  float4 v = reinterpret_cast<const float4*>(src)[k];
  uint2 pk; pk.x = pkbf(v.x, v.y); pk.y = pkbf(v.z, v.w);
  reinterpret_cast<uint2*>(dst)[k] = pk;
}

__device__ inline void cstore(u16* C, size_t i, float v) {
  __hip_bfloat16 h = __float2bfloat16(v); C[i] = *(u16*)&h;
}
__device__ inline void cstore(float* C, size_t i, float v) { C[i] = v; }

// ---------------------------------------------------------------- GEMM 128x128
// C = A * B^T. 256 thr = 4 waves (2M x 2N). Counted vmcnt(4) + raw s_barrier
// pipeline; 0-conflict chunk swizzle. High blocks/CU (3-4) is the measured
// win (r11: 1/CU = -40%; r13/r16: gemm_sm best on both GEMMs).
template<typename OutT>
__global__ __launch_bounds__(256, 4) void gemm_sm(const u16* __restrict__ A,
                                                  const u16* __restrict__ B,
                                                  OutT* __restrict__ C,
                                                  int M, int N, int K) {
  __shared__ u16 As[2][128 * 32];   // 16K
  __shared__ u16 Bs[2][128 * 32];   // 16K

  const int t = threadIdx.x;
  const int lane = t & 63, wid = t >> 6;
  const int l15 = lane & 15, l4 = lane >> 4;
  const int wr = wid >> 1, wc = wid & 1;

  const int nwg = gridDim.x * gridDim.y;
  int lid = blockIdx.y * gridDim.x + blockIdx.x;
  lid = (lid & 7) * (nwg >> 3) + (lid >> 3);
  const int m0 = (lid / gridDim.x) * 128, n0 = (lid % gridDim.x) * 128;

  const int ra0 = t >> 2,         ca0 = (t & 3) ^ ((ra0 >> 1) & 3);
  const int ra1 = (t + 256) >> 2, ca1 = (t & 3) ^ ((ra1 >> 1) & 3);
  const u16* Ag0 = A + (size_t)(m0 + ra0) * K + ca0 * 8;
  const u16* Ag1 = A + (size_t)(m0 + ra1) * K + ca1 * 8;
  const u16* Bg0 = B + (size_t)(n0 + ra0) * K + ca0 * 8;
  const u16* Bg1 = B + (size_t)(n0 + ra1) * K + ca1 * 8;

#define STAGE(k0_, buf_) do {                                                 \
    GLD16(Ag0 + (k0_), &As[buf_][t * 8]);                                     \
    GLD16(Ag1 + (k0_), &As[buf_][2048 + t * 8]);                              \
    GLD16(Bg0 + (k0_), &Bs[buf_][t * 8]);                                     \
    GLD16(Bg1 + (k0_), &Bs[buf_][2048 + t * 8]);                              \
  } while (0)

  const int nk = K >> 5;
  const int ks = (l15 >> 1) & 3;
  const int coff = ((l4 ^ ks) << 3);

  f32x4 acc[4][4] = {};

  STAGE(0, 0);
  STAGE(32, 1);

  for (int j = 0; j < nk; ++j) {
    const int cur = j & 1;
    if (j + 1 < nk) asm volatile("s_waitcnt vmcnt(4)" ::: "memory");
    else            asm volatile("s_waitcnt vmcnt(0)" ::: "memory");
    __builtin_amdgcn_s_barrier();
    __builtin_amdgcn_sched_barrier(0);

    bf16x8 af[4], bfr[4];
#pragma unroll
    for (int mi = 0; mi < 4; ++mi)
      af[mi] = *(const bf16x8*)&As[cur][(wr * 64 + mi * 16 + l15) * 32 + coff];
#pragma unroll
    for (int ni = 0; ni < 4; ++ni)
      bfr[ni] = *(const bf16x8*)&Bs[cur][(wc * 64 + ni * 16 + l15) * 32 + coff];
    __builtin_amdgcn_s_setprio(1);
#pragma unroll
    for (int mi = 0; mi < 4; ++mi)
#pragma unroll
      for (int ni = 0; ni < 4; ++ni)
        acc[mi][ni] = MFMA16(af[mi], bfr[ni], acc[mi][ni]);
    __builtin_amdgcn_s_setprio(0);

    __builtin_amdgcn_s_barrier();
    if (j + 2 < nk) STAGE((j + 2) << 5, cur);
  }

  const int crow = m0 + wr * 64 + (l4 << 2);
  const int ccol = n0 + wc * 64 + l15;
#pragma unroll
  for (int mi = 0; mi < 4; ++mi)
#pragma unroll
    for (int ni = 0; ni < 4; ++ni)
#pragma unroll
      for (int r = 0; r < 4; ++r)
        cstore(C, (size_t)(crow + mi * 16 + r) * N + (ccol + ni * 16), acc[mi][ni][r]);
#undef STAGE
}

// ---------------------------------------------------------------- RMSNorm+RoPE | Vtrans
// Merged launch: blocks [0,20480) do rmsrope (qkv cols < 2560); blocks
// [20480, 20736) do the V transpose (reads cols >= 2560) -> independent.
__global__ __launch_bounds__(256) void rope_vtrans(u16* __restrict__ qkv,
                                                   u16* __restrict__ vt) {
  __shared__ u16 Ls[64 * 130];
  const int bid = blockIdx.x;
  const int t = threadIdx.x;
  if (bid < 20480) {
    const int lane = t & 63;
    const int gw = bid * 4 + (t >> 6);
    const int row = gw / 20;
    const int hd = gw - row * 20;
    const int col = (hd < 16) ? hd * 128 : 2048 + (hd - 16) * 128;
    const size_t base = (size_t)row * 3072 + col;
    float x1 = b2f(qkv[base + lane]);
    float x2 = b2f(qkv[base + 64 + lane]);
    float ss = x1 * x1 + x2 * x2;
#pragma unroll
    for (int off = 32; off >= 1; off >>= 1) ss += __shfl_xor(ss, off, 64);
    const float qsc = (hd < 16) ? (0.08838834764831845f * 1.44269504088896340f)
                                : 1.0f;
    const float sc = rsqrtf(ss * (1.0f / 128.0f) + 1e-6f) * qsc;
    const int pos = row & 2047;
    const float inv_freq = exp2f(-(float)lane * (13.287712379549449f / 64.0f));
    float sn, cs;
    sincosf((float)pos * inv_freq, &sn, &cs);
    const float a = x1 * sc, b2 = x2 * sc;
    __hip_bfloat16 o1 = __float2bfloat16(a * cs - b2 * sn);
    __hip_bfloat16 o2 = __float2bfloat16(a * sn + b2 * cs);
    qkv[base + lane] = *(u16*)&o1;
    qkv[base + 64 + lane] = *(u16*)&o2;
  } else {
    const int vb = bid - 20480;
    const int g = vb & 7, sb = vb >> 3;
    const int b = g >> 2, kvh = g & 3;
    const int vcol = 2560 + kvh * 128;
    {
      const int row = t >> 4, dch = t & 15;
      const u16* src = qkv + (size_t)(b * 2048 + sb * 64 + row) * 3072 + vcol + dch * 8;
#pragma unroll
      for (int it = 0; it < 4; ++it) {
        bf16x8 v = *(const bf16x8*)(src + (size_t)it * 16 * 3072);
        *(bf16x8*)&Ls[(row + it * 16) * 130 + dch * 8] = v;
      }
    }
    __syncthreads();
    const int c = t & 7, d0 = t >> 3;
    const int k0 = 4 * (8 * (c >> 2) + 4 * ((c >> 1) & 1) + (c & 1));
#pragma unroll
    for (int it = 0; it < 4; ++it) {
      const int d = d0 + 32 * it;
      u16 v[8];
#pragma unroll
      for (int e = 0; e < 8; ++e)
        v[e] = Ls[(k0 + (e & 3) + 8 * (e >> 2)) * 130 + d];
      u64 lo = (u64)v[0] | ((u64)v[1] << 16) | ((u64)v[2] << 32) | ((u64)v[3] << 48);
      u64 hi = (u64)v[4] | ((u64)v[5] << 16) | ((u64)v[6] << 32) | ((u64)v[7] << 48);
      u64* dst = (u64*)(vt + ((size_t)g * 128 + d) * 2048 + sb * 64 + c * 8);
      dst[0] = lo; dst[1] = hi;
    }
  }
}

// ---------------------------------------------------------------- flash attention
// r13 structure + T15 double-pipeline: softmax+PV lag the QK^T by one KV
// tile. Per iter: QK MFMA chain for tile kb issues, then the INDEPENDENT
// softmax-finish + register-PV of tile kb-1 executes under it (VALU/MFMA
// dual-pipe), then V[kb] loads into regs (vp) for next iter. Epilogue
// finishes the last tile. Barriers/staging/vmcnt schedule unchanged.
__global__ __launch_bounds__(256, 2) void attn_kernel(const u16* __restrict__ qkv,
                                                      const u16* __restrict__ vt,
                                                      u16* __restrict__ ao) {
  __shared__ u16 Ks[2][64 * 128];   // [k][d], 16B chunks XORed by k&7 (32K)
  __shared__ u16 Vt[2][128 * 64];   // [d][sigma(k)], chunks XORed by d&7 (32K)

  const int t = threadIdx.x;
  const int lane = t & 63, w = t >> 6;
  const int l31 = lane & 31, hi = lane >> 5;
  const int qg = w >> 1, hi2 = w & 1;

  const int bid = blockIdx.x;
  const int g = bid & 7;                  // XCD group = (b, kvh)
  const int b = g >> 2, kvh = g & 3;
  const int idx = bid >> 3;
  const int h = kvh * 4 + (idx & 3);
  const int j = idx >> 2;                 // 0..15 -> pair (j, 31-j)

  const int kcol = 2048 + kvh * 128;
  const u16* vtg = vt + (size_t)g * 128 * 2048;

  const int krow_s = t >> 4, kchk = t & 15;   // K staging (4 GLD/thread)
  const int vd = t >> 3, vc = t & 7;          // V staging (4 GLD/thread)

#define STAGE_K(kb_, buf_) do {                                               \
    const size_t rb_ = (size_t)(b * 2048 + (kb_) * 64);                       \
    _Pragma("unroll")                                                         \
    for (int j_ = 0; j_ < 4; ++j_) {                                          \
      const int row_ = j_ * 16 + krow_s;                                      \
      GLD16(qkv + (rb_ + row_) * 3072 + kcol + ((kchk ^ (row_ & 7)) << 3),    \
            &Ks[buf_][(j_ * 256 + t) << 3]);                                  \
    } } while (0)

#define STAGE_V(kb_, buf_) do {                                               \
    _Pragma("unroll")                                                         \
    for (int j_ = 0; j_ < 4; ++j_) {                                          \
      const int d_ = j_ * 32 + vd;                                            \
      GLD16(vtg + (size_t)d_ * 2048 + (kb_) * 64 + ((vc ^ (d_ & 7)) << 3),    \
            &Vt[buf_][(j_ * 256 + t) << 3]);                                  \
    } } while (0)

  // softmax-finish + PV of tile kbv_ (state in sprev, V in vp0/vp1)
#define FINISH(kbv_) do {                                                     \
    const bool nomask_ = ((kbv_) < qt64) || (hi2 == 0 && qg == 1);            \
    if (!nomask_) {                                                           \
      _Pragma("unroll")                                                       \
      for (int i = 0; i < 16; ++i) {                                          \
        const int kr_ = (kbv_) * 64 + 32 * hi2 + (i & 3) + 8 * (i >> 2) + 4 * hi; \
        sprev[i] = (kr_ <= qrow) ? sprev[i] : -INFINITY;                      \
      }                                                                       \
    }                                                                         \
    float a0_ = fmax3(sprev[0], sprev[1], sprev[2]);                          \
    float a1_ = fmax3(sprev[3], sprev[4], sprev[5]);                          \
    float a2_ = fmax3(sprev[6], sprev[7], sprev[8]);                          \
    float a3_ = fmax3(sprev[9], sprev[10], sprev[11]);                        \
    float a4_ = fmax3(sprev[12], sprev[13], sprev[14]);                       \
    float b0_ = fmax3(a0_, a1_, sprev[15]);                                   \
    float b1_ = fmax3(a2_, a3_, a4_);                                         \
    float pm_ = fmaxf(b0_, b1_);                                              \
    pm_ = fmaxf(pm_, __shfl_xor(pm_, 32));                                    \
    if (!__all(pm_ <= m2 + 8.f)) {                                            \
      const float m2n_ = fmaxf(m2, pm_);                                      \
      const float fc_ = exp2f(m2 - m2n_);                                     \
      m2 = m2n_; l *= fc_;                                                    \
      _Pragma("unroll")                                                       \
      for (int dt = 0; dt < 4; ++dt)                                          \
        _Pragma("unroll")                                                     \
        for (int i = 0; i < 16; ++i) o[dt][i] *= fc_;                         \
    }                                                                         \
    _Pragma("unroll")                                                         \
    for (int i = 0; i < 16; ++i) sprev[i] = exp2f(sprev[i] - m2);             \
    float t8_[8];                                                             \
    _Pragma("unroll")                                                         \
    for (int i = 0; i < 8; ++i) t8_[i] = sprev[i] + sprev[i + 8];             \
    _Pragma("unroll")                                                         \
    for (int i = 0; i < 4; ++i) t8_[i] = t8_[i] + t8_[i + 4];                 \
    l += (t8_[0] + t8_[1]) + (t8_[2] + t8_[3]);                               \
    union PB { u32 wd[4]; bf16x8 v; } p0u_, p1u_;                             \
    _Pragma("unroll")                                                         \
    for (int q_ = 0; q_ < 4; ++q_) {                                          \
      p0u_.wd[q_] = pk2(sprev[2 * q_],     sprev[2 * q_ + 1]);                \
      p1u_.wd[q_] = pk2(sprev[8 + 2 * q_], sprev[8 + 2 * q_ + 1]);            \
    }                                                                         \
    __builtin_amdgcn_s_setprio(1);                                            \
    _Pragma("unroll")                                                         \
    for (int dt = 0; dt < 4; ++dt) {                                          \
      o[dt] = MFMA32(vp0[dt], p0u_.v, o[dt]);                                 \
      o[dt] = MFMA32(vp1[dt], p1u_.v, o[dt]);                                 \
    }                                                                         \
    __builtin_amdgcn_s_setprio(0);                                            \
  } while (0)

  for (int ph = 0; ph < 2; ++ph) {
    const int qt64 = ph ? (31 - j) : j;
    const int q0 = qt64 * 64;
    const int nt = qt64 + 1;
    const int qrow = q0 + 32 * qg + l31;

    // Q fragments (B operand): col=q, k = st*16 + hi*8 + e (pre-scaled)
    bf16x8 qf[8];
    {
      const u16* qp = qkv + (size_t)(b * 2048 + qrow) * 3072 + h * 128 + hi * 8;
#pragma unroll
      for (int st = 0; st < 8; ++st) qf[st] = *(const bf16x8*)(qp + st * 16);
    }

    f32x16 o[4];
#pragma unroll
    for (int dt = 0; dt < 4; ++dt)
#pragma unroll
      for (int i = 0; i < 16; ++i) o[dt][i] = 0.f;
    float m2 = -1e30f, l = 0.f;
    f32x16 sprev;
    bf16x8 vp0[4], vp1[4];

    // prologue: stage batches 0 and 1
    STAGE_K(0, 0);
    STAGE_V(0, 0);
    if (nt > 1) { STAGE_K(1, 1); STAGE_V(1, 1); }

    for (int kb = 0; kb < nt; ++kb) {
      const int cur = kb & 1;
      if (kb + 1 < nt) asm volatile("s_waitcnt vmcnt(8)" ::: "memory");
      else             asm volatile("s_waitcnt vmcnt(0)" ::: "memory");
      __builtin_amdgcn_s_barrier();
      __builtin_amdgcn_sched_barrier(0);

      // ---- S^T = K_half Q^T for tile kb (chain issues, result used next iter)
      f32x16 s;
#pragma unroll
      for (int i = 0; i < 16; ++i) s[i] = 0.f;
      const int kbase = (32 * hi2 + l31) * 128;
      const int ksw = l31 & 7;
      __builtin_amdgcn_s_setprio(1);
#pragma unroll
      for (int st = 0; st < 8; ++st) {
        bf16x8 ka = *(const bf16x8*)&Ks[cur][kbase + (((2 * st + hi) ^ ksw) << 3)];
        s = MFMA32(ka, qf[st], s);
      }
      __builtin_amdgcn_s_setprio(0);

      // ---- finish tile kb-1 under the in-flight QK chain
      if (kb > 0) FINISH(kb - 1);

      // ---- load V[kb] into regs for next iteration's PV
#pragma unroll
      for (int dt = 0; dt < 4; ++dt) {
        const int vrow = (dt * 32 + l31) * 64;
        const int dsw = l31 & 7;
        vp0[dt] = *(const bf16x8*)&Vt[cur][vrow + (((4 * hi2 + hi) ^ dsw) << 3)];
        vp1[dt] = *(const bf16x8*)&Vt[cur][vrow + (((4 * hi2 + 2 + hi) ^ dsw) << 3)];
      }
      sprev = s;

      __builtin_amdgcn_s_barrier();          // all waves done reading buf[cur]
      if (kb + 2 < nt) { STAGE_K(kb + 2, cur); STAGE_V(kb + 2, cur); }
    }

    // ---- epilogue: finish the last tile
    FINISH(nt - 1);

    // ---- in-block merge of the two k-halves (per q-group)
    __syncthreads();                 // all compute done; Ks/Vt reusable
    const float l_tot = l + __shfl_xor(l, 32);
    float* Mrg = (float*)&Ks[0][0];
    float* Mlb = (float*)&Vt[0][0];
    const int sw8 = l31 & 7;
    if (hi2) {
#pragma unroll
      for (int dt = 0; dt < 4; ++dt) {
        const int rbase = ((qg * 4 + dt) * 32 + l31) * 32;
#pragma unroll
        for (int m_ = 0; m_ < 4; ++m_) {
          f32x4 cv;
          cv[0] = o[dt][4 * m_ + 0]; cv[1] = o[dt][4 * m_ + 1];
          cv[2] = o[dt][4 * m_ + 2]; cv[3] = o[dt][4 * m_ + 3];
          *(f32x4*)&Mrg[rbase + (((hi * 4 + m_) ^ sw8) << 2)] = cv;
        }
      }
      if (hi == 0) {
        Mlb[qg * 64 + l31] = m2;
        Mlb[qg * 64 + 32 + l31] = l_tot;
      }
    }
    __syncthreads();
    if (!hi2) {
      const float m1 = Mlb[qg * 64 + l31];
      const float l1 = Mlb[qg * 64 + 32 + l31];
      const float ms = fmaxf(m2, m1);
      const float w0 = exp2f(m2 - ms), w1 = exp2f(m1 - ms);
      const float inv = 1.f / (w0 * l_tot + w1 * l1);
      const float aw0 = w0 * inv, aw1 = w1 * inv;
      const size_t orow = (size_t)(b * 2048 + qrow) * 2048 + h * 128;
#pragma unroll
      for (int dt = 0; dt < 4; ++dt) {
        const int rbase = ((qg * 4 + dt) * 32 + l31) * 32;
#pragma unroll
        for (int m_ = 0; m_ < 4; ++m_) {
          f32x4 o1v = *(const f32x4*)&Mrg[rbase + (((hi * 4 + m_) ^ sw8) << 2)];
          u64 val = 0;
#pragma unroll
          for (int r = 0; r < 4; ++r) {
            __hip_bfloat16 hb =
                __float2bfloat16(aw0 * o[dt][4 * m_ + r] + aw1 * o1v[r]);
            val |= (u64)(*(u16*)&hb) << (16 * r);
          }
          *(u64*)&ao[orow + dt * 32 + 8 * m_ + 4 * hi] = val;
        }
      }
    }
    __syncthreads();                 // protect Mrg/Mlb before next-phase staging
  }
#undef STAGE_K
#undef STAGE_V
#undef FINISH
}

// ---------------------------------------------------------------- launch
extern "C" void kernel_launch(void* const* d_in, const int* in_sizes, int n_in,
                              void* d_out, int out_size, void* d_ws, size_t ws_size,
                              hipStream_t stream) {
  const float* x  = (const float*)d_in[0];
  const float* wq = (const float*)d_in[2];
  const float* wk = (const float*)d_in[3];
  const float* wv = (const float*)d_in[4];
  const float* wo = (const float*)d_in[5];
  float* out = (float*)d_out;

  u16* xb   = (u16*)d_ws;                       // x bf16   [4096][2048]
  u16* wqkv = xb + (size_t)8388608;             // W bf16   [3072][2048]
  u16* qkv  = wqkv + (size_t)6291456;           // qkv      [4096][3072]
  u16* vtg  = qkv + (size_t)12582912;           // V^T      [8][128][2048]
  u16* wob  = vtg + (size_t)2097152;            // wo bf16  [2048][2048]
  u16* ao   = xb;                               // attn out [4096][2048] (reuse xb)

  cast_all<<<18432, 256, 0, stream>>>(x, wq, wk, wv, wo, xb, wqkv, wob);

  gemm_sm<u16><<<dim3(24, 32), 256, 0, stream>>>(xb, wqkv, qkv, 4096, 3072, 2048);

  rope_vtrans<<<20736, 256, 0, stream>>>(qkv, vtg);

  attn_kernel<<<512, 256, 0, stream>>>(qkv, vtg, ao);

  gemm_sm<float><<<dim3(16, 32), 256, 0, stream>>>(ao, wob, out, 4096, 2048, 2048);
}

// Round 18
// 203.232 us; speedup vs baseline: 1.0218x; 1.0218x over previous
//
#include <hip/hip_runtime.h>
#include <hip/hip_bf16.h>

typedef unsigned short u16;
typedef unsigned int   u32;
typedef unsigned long long u64;
typedef __attribute__((ext_vector_type(8))) short bf16x8;
typedef __attribute__((ext_vector_type(4))) float f32x4;
typedef __attribute__((ext_vector_type(16))) float f32x16;

#define MFMA16(a,b,c) __builtin_amdgcn_mfma_f32_16x16x32_bf16((a),(b),(c),0,0,0)
#define MFMA32(a,b,c) __builtin_amdgcn_mfma_f32_32x32x16_bf16((a),(b),(c),0,0,0)

#define GLD16(gp, lp) __builtin_amdgcn_global_load_lds( \
    (const __attribute__((address_space(1))) void*)(gp), \
    (__attribute__((address_space(3))) void*)(lp), 16, 0, 0)

__device__ inline u32 pkbf(float a, float b) {
  __hip_bfloat16 ha = __float2bfloat16(a), hb = __float2bfloat16(b);
  return (u32)(*(u16*)&ha) | ((u32)(*(u16*)&hb) << 16);
}
__device__ inline float b2f(u16 x) {
  __hip_bfloat16 h; *(u16*)&h = x; return __bfloat162float(h);
}
// fast bf16 pair pack: round (+0x8000) then byte-perm the two high halves
__device__ inline u32 pk2(float a, float b) {
  u32 ua = __builtin_bit_cast(u32, a) + 0x8000u;
  u32 ub = __builtin_bit_cast(u32, b) + 0x8000u;
  return __builtin_amdgcn_perm(ub, ua, 0x07060302u);
}
__device__ inline float fmax3(float a, float b, float c) {
  return fmaxf(fmaxf(a, b), c);
}

// ---------------------------------------------------------------- fused casts
__global__ __launch_bounds__(256) void cast_all(const float* __restrict__ x,
                                                const float* __restrict__ wq,
                                                const float* __restrict__ wk,
                                                const float* __restrict__ wv,
                                                const float* __restrict__ wo,
                                                u16* __restrict__ xb,
                                                u16* __restrict__ wqkv,
                                                u16* __restrict__ wob) {
  int i = blockIdx.x * 256 + threadIdx.x;
  const float* src; u16* dst; int off;
  if (i < 2097152)      { src = x;  dst = xb;                 off = 0; }
  else if (i < 3145728) { src = wq; dst = wqkv;               off = 2097152; }
  else if (i < 3407872) { src = wk; dst = wqkv + 4194304;     off = 3145728; }
  else if (i < 3670016) { src = wv; dst = wqkv + 5242880;     off = 3407872; }
  else                  { src = wo; dst = wob;                off = 3670016; }
  const int k = i - off;
  float4 v = reinterpret_cast<const float4*>(src)[k];
  uint2 pk; pk.x = pkbf(v.x, v.y); pk.y = pkbf(v.z, v.w);
  reinterpret_cast<uint2*>(dst)[k] = pk;
}

__device__ inline void cstore(u16* C, size_t i, float v) {
  __hip_bfloat16 h = __float2bfloat16(v); C[i] = *(u16*)&h;
}
__device__ inline void cstore(float* C, size_t i, float v) { C[i] = v; }

// ---------------------------------------------------------------- GEMM 128x128
// C = A * B^T. 256 thr = 4 waves (2M x 2N). Counted vmcnt(4) + raw s_barrier
// pipeline; 0-conflict chunk swizzle. High blocks/CU (3-4) is the measured
// win (r11: 1/CU = -40%; r13/r16: gemm_sm best on both GEMMs).
// If Vt != nullptr, tiles with n0 >= 2560 (the V output columns) are written
// directly to vt[g=b*4+kvh][d=128][s=2048] in sigma-order (fused vtrans):
// srow=4a+r -> p = 32*a5 + 16*a4 + 8*a2 + 4*a3 + r within each 64-group.
template<typename OutT>
__global__ __launch_bounds__(256, 4) void gemm_sm(const u16* __restrict__ A,
                                                  const u16* __restrict__ B,
                                                  OutT* __restrict__ C,
                                                  u16* __restrict__ Vt,
                                                  int M, int N, int K) {
  __shared__ u16 As[2][128 * 32];   // 16K
  __shared__ u16 Bs[2][128 * 32];   // 16K

  const int t = threadIdx.x;
  const int lane = t & 63, wid = t >> 6;
  const int l15 = lane & 15, l4 = lane >> 4;
  const int wr = wid >> 1, wc = wid & 1;

  const int nwg = gridDim.x * gridDim.y;
  int lid = blockIdx.y * gridDim.x + blockIdx.x;
  lid = (lid & 7) * (nwg >> 3) + (lid >> 3);
  const int m0 = (lid / gridDim.x) * 128, n0 = (lid % gridDim.x) * 128;

  const int ra0 = t >> 2,         ca0 = (t & 3) ^ ((ra0 >> 1) & 3);
  const int ra1 = (t + 256) >> 2, ca1 = (t & 3) ^ ((ra1 >> 1) & 3);
  const u16* Ag0 = A + (size_t)(m0 + ra0) * K + ca0 * 8;
  const u16* Ag1 = A + (size_t)(m0 + ra1) * K + ca1 * 8;
  const u16* Bg0 = B + (size_t)(n0 + ra0) * K + ca0 * 8;
  const u16* Bg1 = B + (size_t)(n0 + ra1) * K + ca1 * 8;

#define STAGE(k0_, buf_) do {                                                 \
    GLD16(Ag0 + (k0_), &As[buf_][t * 8]);                                     \
    GLD16(Ag1 + (k0_), &As[buf_][2048 + t * 8]);                              \
    GLD16(Bg0 + (k0_), &Bs[buf_][t * 8]);                                     \
    GLD16(Bg1 + (k0_), &Bs[buf_][2048 + t * 8]);                              \
  } while (0)

  const int nk = K >> 5;
  const int ks = (l15 >> 1) & 3;
  const int coff = ((l4 ^ ks) << 3);

  f32x4 acc[4][4] = {};

  STAGE(0, 0);
  STAGE(32, 1);

  for (int j = 0; j < nk; ++j) {
    const int cur = j & 1;
    if (j + 1 < nk) asm volatile("s_waitcnt vmcnt(4)" ::: "memory");
    else            asm volatile("s_waitcnt vmcnt(0)" ::: "memory");
    __builtin_amdgcn_s_barrier();
    __builtin_amdgcn_sched_barrier(0);

    bf16x8 af[4], bfr[4];
#pragma unroll
    for (int mi = 0; mi < 4; ++mi)
      af[mi] = *(const bf16x8*)&As[cur][(wr * 64 + mi * 16 + l15) * 32 + coff];
#pragma unroll
    for (int ni = 0; ni < 4; ++ni)
      bfr[ni] = *(const bf16x8*)&Bs[cur][(wc * 64 + ni * 16 + l15) * 32 + coff];
    __builtin_amdgcn_s_setprio(1);
#pragma unroll
    for (int mi = 0; mi < 4; ++mi)
#pragma unroll
      for (int ni = 0; ni < 4; ++ni)
        acc[mi][ni] = MFMA16(af[mi], bfr[ni], acc[mi][ni]);
    __builtin_amdgcn_s_setprio(0);

    __builtin_amdgcn_s_barrier();
    if (j + 2 < nk) STAGE((j + 2) << 5, cur);
  }

  const int crow = m0 + wr * 64 + (l4 << 2);
  const int ccol = n0 + wc * 64 + l15;
  if (Vt != nullptr && n0 >= 2560) {
    // fused V transpose: write sigma-ordered vt[g][d][s]
    const int kvh = (n0 - 2560) >> 7;
    const int d0 = wc * 64 + l15;
#pragma unroll
    for (int mi = 0; mi < 4; ++mi) {
      const int s = crow + mi * 16;
      const int batch = s >> 11, srow = s & 2047;
      const int ko = srow & 60;
      const int p = 32 * ((ko >> 5) & 1) + 16 * ((ko >> 4) & 1)
                  + 8 * ((ko >> 2) & 1) + 4 * ((ko >> 3) & 1);
      u16* dst = Vt + ((size_t)((batch * 4 + kvh) * 128 + d0)) * 2048
               + (srow & ~63) + p;
#pragma unroll
      for (int ni = 0; ni < 4; ++ni) {
        u64 val = 0;
#pragma unroll
        for (int r = 0; r < 4; ++r) {
          __hip_bfloat16 hb = __float2bfloat16(acc[mi][ni][r]);
          val |= (u64)(*(u16*)&hb) << (16 * r);
        }
        *(u64*)(dst + (size_t)ni * 16 * 2048) = val;
      }
    }
  } else {
#pragma unroll
    for (int mi = 0; mi < 4; ++mi)
#pragma unroll
      for (int ni = 0; ni < 4; ++ni)
#pragma unroll
        for (int r = 0; r < 4; ++r)
          cstore(C, (size_t)(crow + mi * 16 + r) * N + (ccol + ni * 16),
                 acc[mi][ni][r]);
  }
#undef STAGE
}

// ---------------------------------------------------------------- RMSNorm + RoPE
// q heads pre-scaled by (1/sqrt(128))*log2(e) -> QK^T lands in exp2 domain.
__global__ __launch_bounds__(256) void rmsrope_kernel(u16* __restrict__ qkv) {
  const int t = threadIdx.x;
  const int lane = t & 63;
  const int gw = blockIdx.x * 4 + (t >> 6);
  const int row = gw / 20;
  const int hd = gw - row * 20;
  const int col = (hd < 16) ? hd * 128 : 2048 + (hd - 16) * 128;
  const size_t base = (size_t)row * 3072 + col;
  float x1 = b2f(qkv[base + lane]);
  float x2 = b2f(qkv[base + 64 + lane]);
  float ss = x1 * x1 + x2 * x2;
#pragma unroll
  for (int off = 32; off >= 1; off >>= 1) ss += __shfl_xor(ss, off, 64);
  const float qsc = (hd < 16) ? (0.08838834764831845f * 1.44269504088896340f)
                              : 1.0f;
  const float sc = rsqrtf(ss * (1.0f / 128.0f) + 1e-6f) * qsc;
  const int pos = row & 2047;
  const float inv_freq = exp2f(-(float)lane * (13.287712379549449f / 64.0f));
  float sn, cs;
  sincosf((float)pos * inv_freq, &sn, &cs);
  const float a = x1 * sc, b2 = x2 * sc;
  __hip_bfloat16 o1 = __float2bfloat16(a * cs - b2 * sn);
  __hip_bfloat16 o2 = __float2bfloat16(a * sn + b2 * cs);
  qkv[base + lane] = *(u16*)&o1;
  qkv[base + 64 + lane] = *(u16*)&o2;
}

// ---------------------------------------------------------------- flash attention
// (measured best, r10/r13): 512 blocks x 256 thr = 4 waves (2 qg x 2
// k-halves); q64-tile pair (j, 31-j) sequential (33 iters); counted vmcnt(8)
// pipeline, 2 barriers/iter; zero-shuffle PV via sigma-ordered vt; XOR bank
// swizzles; defer-max; exp2-domain Q prescale.
__global__ __launch_bounds__(256, 2) void attn_kernel(const u16* __restrict__ qkv,
                                                      const u16* __restrict__ vt,
                                                      u16* __restrict__ ao) {
  __shared__ u16 Ks[2][64 * 128];   // [k][d], 16B chunks XORed by k&7 (32K)
  __shared__ u16 Vt[2][128 * 64];   // [d][sigma(k)], chunks XORed by d&7 (32K)

  const int t = threadIdx.x;
  const int lane = t & 63, w = t >> 6;
  const int l31 = lane & 31, hi = lane >> 5;
  const int qg = w >> 1, hi2 = w & 1;

  const int bid = blockIdx.x;
  const int g = bid & 7;                  // XCD group = (b, kvh)
  const int b = g >> 2, kvh = g & 3;
  const int idx = bid >> 3;
  const int h = kvh * 4 + (idx & 3);
  const int j = idx >> 2;                 // 0..15 -> pair (j, 31-j)

  const int kcol = 2048 + kvh * 128;
  const u16* vtg = vt + (size_t)g * 128 * 2048;

  const int krow_s = t >> 4, kchk = t & 15;   // K staging (4 GLD/thread)
  const int vd = t >> 3, vc = t & 7;          // V staging (4 GLD/thread)

#define STAGE_K(kb_, buf_) do {                                               \
    const size_t rb_ = (size_t)(b * 2048 + (kb_) * 64);                       \
    _Pragma("unroll")                                                         \
    for (int j_ = 0; j_ < 4; ++j_) {                                          \
      const int row_ = j_ * 16 + krow_s;                                      \
      GLD16(qkv + (rb_ + row_) * 3072 + kcol + ((kchk ^ (row_ & 7)) << 3),    \
            &Ks[buf_][(j_ * 256 + t) << 3]);                                  \
    } } while (0)

#define STAGE_V(kb_, buf_) do {                                               \
    _Pragma("unroll")                                                         \
    for (int j_ = 0; j_ < 4; ++j_) {                                          \
      const int d_ = j_ * 32 + vd;                                            \
      GLD16(vtg + (size_t)d_ * 2048 + (kb_) * 64 + ((vc ^ (d_ & 7)) << 3),    \
            &Vt[buf_][(j_ * 256 + t) << 3]);                                  \
    } } while (0)

  for (int ph = 0; ph < 2; ++ph) {
    const int qt64 = ph ? (31 - j) : j;
    const int q0 = qt64 * 64;
    const int nt = qt64 + 1;
    const int qrow = q0 + 32 * qg + l31;

    // Q fragments (B operand): col=q, k = st*16 + hi*8 + e (pre-scaled)
    bf16x8 qf[8];
    {
      const u16* qp = qkv + (size_t)(b * 2048 + qrow) * 3072 + h * 128 + hi * 8;
#pragma unroll
      for (int st = 0; st < 8; ++st) qf[st] = *(const bf16x8*)(qp + st * 16);
    }

    f32x16 o[4];
#pragma unroll
    for (int dt = 0; dt < 4; ++dt)
#pragma unroll
      for (int i = 0; i < 16; ++i) o[dt][i] = 0.f;
    float m2 = -1e30f, l = 0.f;

    // prologue: stage batches 0 and 1
    STAGE_K(0, 0);
    STAGE_V(0, 0);
    if (nt > 1) { STAGE_K(1, 1); STAGE_V(1, 1); }

    for (int kb = 0; kb < nt; ++kb) {
      const int cur = kb & 1;
      if (kb + 1 < nt) asm volatile("s_waitcnt vmcnt(8)" ::: "memory");
      else             asm volatile("s_waitcnt vmcnt(0)" ::: "memory");
      __builtin_amdgcn_s_barrier();
      __builtin_amdgcn_sched_barrier(0);

      // ---- S^T = K_half Q^T  (rows k of this wave's 32-half, cols q)
      f32x16 s;
#pragma unroll
      for (int i = 0; i < 16; ++i) s[i] = 0.f;
      const int kbase = (32 * hi2 + l31) * 128;
      const int ksw = l31 & 7;
      __builtin_amdgcn_s_setprio(1);
#pragma unroll
      for (int st = 0; st < 8; ++st) {
        bf16x8 ka = *(const bf16x8*)&Ks[cur][kbase + (((2 * st + hi) ^ ksw) << 3)];
        s = MFMA32(ka, qf[st], s);
      }
      __builtin_amdgcn_s_setprio(0);

      // ---- mask (diag only), max3-tree row max
      const bool nomask = (kb < qt64) || (hi2 == 0 && qg == 1);
      if (!nomask) {
#pragma unroll
        for (int i = 0; i < 16; ++i) {
          const int kr = kb * 64 + 32 * hi2 + (i & 3) + 8 * (i >> 2) + 4 * hi;
          s[i] = (kr <= qrow) ? s[i] : -INFINITY;
        }
      }
      float a0 = fmax3(s[0], s[1], s[2]);
      float a1 = fmax3(s[3], s[4], s[5]);
      float a2 = fmax3(s[6], s[7], s[8]);
      float a3 = fmax3(s[9], s[10], s[11]);
      float a4 = fmax3(s[12], s[13], s[14]);
      float b0 = fmax3(a0, a1, s[15]);
      float b1 = fmax3(a2, a3, a4);
      float pm = fmaxf(b0, b1);
      pm = fmaxf(pm, __shfl_xor(pm, 32));
      // ---- defer-max rescale
      if (!__all(pm <= m2 + 8.f)) {
        const float m2n = fmaxf(m2, pm);
        const float fc = exp2f(m2 - m2n);
        m2 = m2n; l *= fc;
#pragma unroll
        for (int dt = 0; dt < 4; ++dt)
#pragma unroll
          for (int i = 0; i < 16; ++i) o[dt][i] *= fc;
      }
      // ---- P = exp2(z - m2), tree local sum (cross-hi deferred)
#pragma unroll
      for (int i = 0; i < 16; ++i) s[i] = exp2f(s[i] - m2);
      float t8[8];
#pragma unroll
      for (int i = 0; i < 8; ++i) t8[i] = s[i] + s[i + 8];
#pragma unroll
      for (int i = 0; i < 4; ++i) t8[i] = t8[i] + t8[i + 4];
      l += (t8[0] + t8[1]) + (t8[2] + t8[3]);
      // ---- P C-regs -> B-operand directly (sigma order, perm pack)
      union PB { u32 wd[4]; bf16x8 v; } p0u, p1u;
#pragma unroll
      for (int q_ = 0; q_ < 4; ++q_) {
        p0u.wd[q_] = pk2(s[2 * q_],     s[2 * q_ + 1]);
        p1u.wd[q_] = pk2(s[8 + 2 * q_], s[8 + 2 * q_ + 1]);
      }
      // ---- O^T += V^T_half P_half  (rows d, cols q)
      __builtin_amdgcn_s_setprio(1);
#pragma unroll
      for (int dt = 0; dt < 4; ++dt) {
        const int vrow = (dt * 32 + l31) * 64;
        const int dsw = l31 & 7;
        bf16x8 va0 = *(const bf16x8*)&Vt[cur][vrow + (((4 * hi2 + hi) ^ dsw) << 3)];
        o[dt] = MFMA32(va0, p0u.v, o[dt]);
        bf16x8 va1 = *(const bf16x8*)&Vt[cur][vrow + (((4 * hi2 + 2 + hi) ^ dsw) << 3)];
        o[dt] = MFMA32(va1, p1u.v, o[dt]);
      }
      __builtin_amdgcn_s_setprio(0);

      __builtin_amdgcn_s_barrier();          // all waves done reading buf[cur]
      if (kb + 2 < nt) { STAGE_K(kb + 2, cur); STAGE_V(kb + 2, cur); }
    }

    // ---- in-block merge of the two k-halves (per q-group)
    __syncthreads();                 // all compute done; Ks/Vt reusable
    const float l_tot = l + __shfl_xor(l, 32);
    float* Mrg = (float*)&Ks[0][0];
    float* Mlb = (float*)&Vt[0][0];
    const int sw8 = l31 & 7;
    if (hi2) {
#pragma unroll
      for (int dt = 0; dt < 4; ++dt) {
        const int rbase = ((qg * 4 + dt) * 32 + l31) * 32;
#pragma unroll
        for (int m_ = 0; m_ < 4; ++m_) {
          f32x4 cv;
          cv[0] = o[dt][4 * m_ + 0]; cv[1] = o[dt][4 * m_ + 1];
          cv[2] = o[dt][4 * m_ + 2]; cv[3] = o[dt][4 * m_ + 3];
          *(f32x4*)&Mrg[rbase + (((hi * 4 + m_) ^ sw8) << 2)] = cv;
        }
      }
      if (hi == 0) {
        Mlb[qg * 64 + l31] = m2;
        Mlb[qg * 64 + 32 + l31] = l_tot;
      }
    }
    __syncthreads();
    if (!hi2) {
      const float m1 = Mlb[qg * 64 + l31];
      const float l1 = Mlb[qg * 64 + 32 + l31];
      const float ms = fmaxf(m2, m1);
      const float w0 = exp2f(m2 - ms), w1 = exp2f(m1 - ms);
      const float inv = 1.f / (w0 * l_tot + w1 * l1);
      const float aw0 = w0 * inv, aw1 = w1 * inv;
      const size_t orow = (size_t)(b * 2048 + qrow) * 2048 + h * 128;
#pragma unroll
      for (int dt = 0; dt < 4; ++dt) {
        const int rbase = ((qg * 4 + dt) * 32 + l31) * 32;
#pragma unroll
        for (int m_ = 0; m_ < 4; ++m_) {
          f32x4 o1v = *(const f32x4*)&Mrg[rbase + (((hi * 4 + m_) ^ sw8) << 2)];
          u64 val = 0;
#pragma unroll
          for (int r = 0; r < 4; ++r) {
            __hip_bfloat16 hb =
                __float2bfloat16(aw0 * o[dt][4 * m_ + r] + aw1 * o1v[r]);
            val |= (u64)(*(u16*)&hb) << (16 * r);
          }
          *(u64*)&ao[orow + dt * 32 + 8 * m_ + 4 * hi] = val;
        }
      }
    }
    __syncthreads();                 // protect Mrg/Mlb before next-phase staging
  }
#undef STAGE_K
#undef STAGE_V
}

// ---------------------------------------------------------------- launch
extern "C" void kernel_launch(void* const* d_in, const int* in_sizes, int n_in,
                              void* d_out, int out_size, void* d_ws, size_t ws_size,
                              hipStream_t stream) {
  const float* x  = (const float*)d_in[0];
  const float* wq = (const float*)d_in[2];
  const float* wk = (const float*)d_in[3];
  const float* wv = (const float*)d_in[4];
  const float* wo = (const float*)d_in[5];
  float* out = (float*)d_out;

  u16* xb   = (u16*)d_ws;                       // x bf16   [4096][2048]
  u16* wqkv = xb + (size_t)8388608;             // W bf16   [3072][2048]
  u16* qkv  = wqkv + (size_t)6291456;           // qkv      [4096][3072] (V cols unused)
  u16* vtg  = qkv + (size_t)12582912;           // V^T      [8][128][2048]
  u16* wob  = vtg + (size_t)2097152;            // wo bf16  [2048][2048]
  u16* ao   = xb;                               // attn out [4096][2048] (reuse xb)

  cast_all<<<18432, 256, 0, stream>>>(x, wq, wk, wv, wo, xb, wqkv, wob);

  // gemm1: V-column tiles (n0 >= 2560) written directly to vtg (fused vtrans)
  gemm_sm<u16><<<dim3(24, 32), 256, 0, stream>>>(xb, wqkv, qkv, vtg,
                                                 4096, 3072, 2048);

  rmsrope_kernel<<<20480, 256, 0, stream>>>(qkv);

  attn_kernel<<<512, 256, 0, stream>>>(qkv, vtg, ao);

  gemm_sm<float><<<dim3(16, 32), 256, 0, stream>>>(ao, wob, out, nullptr,
                                                   4096, 2048, 2048);
}

// Round 19
// 200.367 us; speedup vs baseline: 1.0364x; 1.0143x over previous
//
#include <hip/hip_runtime.h>
#include <hip/hip_bf16.h>

typedef unsigned short u16;
typedef unsigned int   u32;
typedef unsigned long long u64;
typedef __attribute__((ext_vector_type(8))) short bf16x8;
typedef __attribute__((ext_vector_type(4))) float f32x4;
typedef __attribute__((ext_vector_type(16))) float f32x16;

#define MFMA16(a,b,c) __builtin_amdgcn_mfma_f32_16x16x32_bf16((a),(b),(c),0,0,0)
#define MFMA32(a,b,c) __builtin_amdgcn_mfma_f32_32x32x16_bf16((a),(b),(c),0,0,0)

#define GLD16(gp, lp) __builtin_amdgcn_global_load_lds( \
    (const __attribute__((address_space(1))) void*)(gp), \
    (__attribute__((address_space(3))) void*)(lp), 16, 0, 0)

__device__ inline u32 pkbf(float a, float b) {
  __hip_bfloat16 ha = __float2bfloat16(a), hb = __float2bfloat16(b);
  return (u32)(*(u16*)&ha) | ((u32)(*(u16*)&hb) << 16);
}
__device__ inline float b2f(u16 x) {
  __hip_bfloat16 h; *(u16*)&h = x; return __bfloat162float(h);
}
// fast bf16 pair pack: round (+0x8000) then byte-perm the two high halves
__device__ inline u32 pk2(float a, float b) {
  u32 ua = __builtin_bit_cast(u32, a) + 0x8000u;
  u32 ub = __builtin_bit_cast(u32, b) + 0x8000u;
  return __builtin_amdgcn_perm(ub, ua, 0x07060302u);
}
__device__ inline float fmax3(float a, float b, float c) {
  return fmaxf(fmaxf(a, b), c);
}

// ---------------------------------------------------------------- fused casts
__global__ __launch_bounds__(256) void cast_all(const float* __restrict__ x,
                                                const float* __restrict__ wq,
                                                const float* __restrict__ wk,
                                                const float* __restrict__ wv,
                                                const float* __restrict__ wo,
                                                u16* __restrict__ xb,
                                                u16* __restrict__ wqkv,
                                                u16* __restrict__ wob) {
  int i = blockIdx.x * 256 + threadIdx.x;
  const float* src; u16* dst; int off;
  if (i < 2097152)      { src = x;  dst = xb;                 off = 0; }
  else if (i < 3145728) { src = wq; dst = wqkv;               off = 2097152; }
  else if (i < 3407872) { src = wk; dst = wqkv + 4194304;     off = 3145728; }
  else if (i < 3670016) { src = wv; dst = wqkv + 5242880;     off = 3407872; }
  else                  { src = wo; dst = wob;                off = 3670016; }
  const int k = i - off;
  float4 v = reinterpret_cast<const float4*>(src)[k];
  uint2 pk; pk.x = pkbf(v.x, v.y); pk.y = pkbf(v.z, v.w);
  reinterpret_cast<uint2*>(dst)[k] = pk;
}

__device__ inline void cstore(u16* C, size_t i, float v) {
  __hip_bfloat16 h = __float2bfloat16(v); C[i] = *(u16*)&h;
}
__device__ inline void cstore(float* C, size_t i, float v) { C[i] = v; }

// ---------------------------------------------------------------- GEMM 128x128
// C = A * B^T. 256 thr = 4 waves (2M x 2N). Counted vmcnt(4) + raw s_barrier
// pipeline; 0-conflict chunk swizzle. High blocks/CU (3-4) is the measured
// win (r11: 1/CU = -40%; r13/r16: gemm_sm best on both GEMMs).
template<typename OutT>
__global__ __launch_bounds__(256, 4) void gemm_sm(const u16* __restrict__ A,
                                                  const u16* __restrict__ B,
                                                  OutT* __restrict__ C,
                                                  int M, int N, int K) {
  __shared__ u16 As[2][128 * 32];   // 16K
  __shared__ u16 Bs[2][128 * 32];   // 16K

  const int t = threadIdx.x;
  const int lane = t & 63, wid = t >> 6;
  const int l15 = lane & 15, l4 = lane >> 4;
  const int wr = wid >> 1, wc = wid & 1;

  const int nwg = gridDim.x * gridDim.y;
  int lid = blockIdx.y * gridDim.x + blockIdx.x;
  lid = (lid & 7) * (nwg >> 3) + (lid >> 3);
  const int m0 = (lid / gridDim.x) * 128, n0 = (lid % gridDim.x) * 128;

  const int ra0 = t >> 2,         ca0 = (t & 3) ^ ((ra0 >> 1) & 3);
  const int ra1 = (t + 256) >> 2, ca1 = (t & 3) ^ ((ra1 >> 1) & 3);
  const u16* Ag0 = A + (size_t)(m0 + ra0) * K + ca0 * 8;
  const u16* Ag1 = A + (size_t)(m0 + ra1) * K + ca1 * 8;
  const u16* Bg0 = B + (size_t)(n0 + ra0) * K + ca0 * 8;
  const u16* Bg1 = B + (size_t)(n0 + ra1) * K + ca1 * 8;

#define STAGE(k0_, buf_) do {                                                 \
    GLD16(Ag0 + (k0_), &As[buf_][t * 8]);                                     \
    GLD16(Ag1 + (k0_), &As[buf_][2048 + t * 8]);                              \
    GLD16(Bg0 + (k0_), &Bs[buf_][t * 8]);                                     \
    GLD16(Bg1 + (k0_), &Bs[buf_][2048 + t * 8]);                              \
  } while (0)

  const int nk = K >> 5;
  const int ks = (l15 >> 1) & 3;
  const int coff = ((l4 ^ ks) << 3);

  f32x4 acc[4][4] = {};

  STAGE(0, 0);
  STAGE(32, 1);

  for (int j = 0; j < nk; ++j) {
    const int cur = j & 1;
    if (j + 1 < nk) asm volatile("s_waitcnt vmcnt(4)" ::: "memory");
    else            asm volatile("s_waitcnt vmcnt(0)" ::: "memory");
    __builtin_amdgcn_s_barrier();
    __builtin_amdgcn_sched_barrier(0);

    bf16x8 af[4], bfr[4];
#pragma unroll
    for (int mi = 0; mi < 4; ++mi)
      af[mi] = *(const bf16x8*)&As[cur][(wr * 64 + mi * 16 + l15) * 32 + coff];
#pragma unroll
    for (int ni = 0; ni < 4; ++ni)
      bfr[ni] = *(const bf16x8*)&Bs[cur][(wc * 64 + ni * 16 + l15) * 32 + coff];
    __builtin_amdgcn_s_setprio(1);
#pragma unroll
    for (int mi = 0; mi < 4; ++mi)
#pragma unroll
      for (int ni = 0; ni < 4; ++ni)
        acc[mi][ni] = MFMA16(af[mi], bfr[ni], acc[mi][ni]);
    __builtin_amdgcn_s_setprio(0);

    __builtin_amdgcn_s_barrier();
    if (j + 2 < nk) STAGE((j + 2) << 5, cur);
  }

  const int crow = m0 + wr * 64 + (l4 << 2);
  const int ccol = n0 + wc * 64 + l15;
#pragma unroll
  for (int mi = 0; mi < 4; ++mi)
#pragma unroll
    for (int ni = 0; ni < 4; ++ni)
#pragma unroll
      for (int r = 0; r < 4; ++r)
        cstore(C, (size_t)(crow + mi * 16 + r) * N + (ccol + ni * 16), acc[mi][ni][r]);
#undef STAGE
}

// ---------------------------------------------------------------- RMSNorm+RoPE | Vtrans
// Merged launch: blocks [0,20480) do rmsrope (qkv cols < 2560); blocks
// [20480, 20736) do the V transpose (reads cols >= 2560) -> independent.
__global__ __launch_bounds__(256) void rope_vtrans(u16* __restrict__ qkv,
                                                   u16* __restrict__ vt) {
  __shared__ u16 Ls[64 * 130];
  const int bid = blockIdx.x;
  const int t = threadIdx.x;
  if (bid < 20480) {
    const int lane = t & 63;
    const int gw = bid * 4 + (t >> 6);
    const int row = gw / 20;
    const int hd = gw - row * 20;
    const int col = (hd < 16) ? hd * 128 : 2048 + (hd - 16) * 128;
    const size_t base = (size_t)row * 3072 + col;
    float x1 = b2f(qkv[base + lane]);
    float x2 = b2f(qkv[base + 64 + lane]);
    float ss = x1 * x1 + x2 * x2;
#pragma unroll
    for (int off = 32; off >= 1; off >>= 1) ss += __shfl_xor(ss, off, 64);
    const float qsc = (hd < 16) ? (0.08838834764831845f * 1.44269504088896340f)
                                : 1.0f;
    const float sc = rsqrtf(ss * (1.0f / 128.0f) + 1e-6f) * qsc;
    const int pos = row & 2047;
    const float inv_freq = exp2f(-(float)lane * (13.287712379549449f / 64.0f));
    float sn, cs;
    sincosf((float)pos * inv_freq, &sn, &cs);
    const float a = x1 * sc, b2 = x2 * sc;
    __hip_bfloat16 o1 = __float2bfloat16(a * cs - b2 * sn);
    __hip_bfloat16 o2 = __float2bfloat16(a * sn + b2 * cs);
    qkv[base + lane] = *(u16*)&o1;
    qkv[base + 64 + lane] = *(u16*)&o2;
  } else {
    const int vb = bid - 20480;
    const int g = vb & 7, sb = vb >> 3;
    const int b = g >> 2, kvh = g & 3;
    const int vcol = 2560 + kvh * 128;
    {
      const int row = t >> 4, dch = t & 15;
      const u16* src = qkv + (size_t)(b * 2048 + sb * 64 + row) * 3072 + vcol + dch * 8;
#pragma unroll
      for (int it = 0; it < 4; ++it) {
        bf16x8 v = *(const bf16x8*)(src + (size_t)it * 16 * 3072);
        *(bf16x8*)&Ls[(row + it * 16) * 130 + dch * 8] = v;
      }
    }
    __syncthreads();
    const int c = t & 7, d0 = t >> 3;
    const int k0 = 4 * (8 * (c >> 2) + 4 * ((c >> 1) & 1) + (c & 1));
#pragma unroll
    for (int it = 0; it < 4; ++it) {
      const int d = d0 + 32 * it;
      u16 v[8];
#pragma unroll
      for (int e = 0; e < 8; ++e)
        v[e] = Ls[(k0 + (e & 3) + 8 * (e >> 2)) * 130 + d];
      u64 lo = (u64)v[0] | ((u64)v[1] << 16) | ((u64)v[2] << 32) | ((u64)v[3] << 48);
      u64 hi = (u64)v[4] | ((u64)v[5] << 16) | ((u64)v[6] << 32) | ((u64)v[7] << 48);
      u64* dst = (u64*)(vt + ((size_t)g * 128 + d) * 2048 + sb * 64 + c * 8);
      dst[0] = lo; dst[1] = hi;
    }
  }
}

// ---------------------------------------------------------------- flash attention
// r16 base + deferred cross-half max: the __shfl_xor(pm,32) ds_bpermute is
// removed from the per-iter critical path — __all(pm_local <= m2+8) over 64
// lanes is equivalent to testing the full row max; the shuffle runs only
// inside the rare rescale branch (m2 stays wave-consistent: updates are
// wave-uniform and use the full max).
__global__ __launch_bounds__(256, 2) void attn_kernel(const u16* __restrict__ qkv,
                                                      const u16* __restrict__ vt,
                                                      u16* __restrict__ ao) {
  __shared__ u16 Ks[2][64 * 128];   // [k][d], 16B chunks XORed by k&7 (32K)
  __shared__ u16 Vt[2][128 * 64];   // [d][sigma(k)], chunks XORed by d&7 (32K)

  const int t = threadIdx.x;
  const int lane = t & 63, w = t >> 6;
  const int l31 = lane & 31, hi = lane >> 5;
  const int qg = w >> 1, hi2 = w & 1;

  const int bid = blockIdx.x;
  const int g = bid & 7;                  // XCD group = (b, kvh)
  const int b = g >> 2, kvh = g & 3;
  const int idx = bid >> 3;
  const int h = kvh * 4 + (idx & 3);
  const int j = idx >> 2;                 // 0..15 -> pair (j, 31-j)

  const int kcol = 2048 + kvh * 128;
  const u16* vtg = vt + (size_t)g * 128 * 2048;

  const int krow_s = t >> 4, kchk = t & 15;   // K staging (4 GLD/thread)
  const int vd = t >> 3, vc = t & 7;          // V staging (4 GLD/thread)

#define STAGE_K(kb_, buf_) do {                                               \
    const size_t rb_ = (size_t)(b * 2048 + (kb_) * 64);                       \
    _Pragma("unroll")                                                         \
    for (int j_ = 0; j_ < 4; ++j_) {                                          \
      const int row_ = j_ * 16 + krow_s;                                      \
      GLD16(qkv + (rb_ + row_) * 3072 + kcol + ((kchk ^ (row_ & 7)) << 3),    \
            &Ks[buf_][(j_ * 256 + t) << 3]);                                  \
    } } while (0)

#define STAGE_V(kb_, buf_) do {                                               \
    _Pragma("unroll")                                                         \
    for (int j_ = 0; j_ < 4; ++j_) {                                          \
      const int d_ = j_ * 32 + vd;                                            \
      GLD16(vtg + (size_t)d_ * 2048 + (kb_) * 64 + ((vc ^ (d_ & 7)) << 3),    \
            &Vt[buf_][(j_ * 256 + t) << 3]);                                  \
    } } while (0)

  for (int ph = 0; ph < 2; ++ph) {
    const int qt64 = ph ? (31 - j) : j;
    const int q0 = qt64 * 64;
    const int nt = qt64 + 1;
    const int qrow = q0 + 32 * qg + l31;

    // Q fragments (B operand): col=q, k = st*16 + hi*8 + e (pre-scaled)
    bf16x8 qf[8];
    {
      const u16* qp = qkv + (size_t)(b * 2048 + qrow) * 3072 + h * 128 + hi * 8;
#pragma unroll
      for (int st = 0; st < 8; ++st) qf[st] = *(const bf16x8*)(qp + st * 16);
    }

    f32x16 o[4];
#pragma unroll
    for (int dt = 0; dt < 4; ++dt)
#pragma unroll
      for (int i = 0; i < 16; ++i) o[dt][i] = 0.f;
    float m2 = -1e30f, l = 0.f;

    // prologue: stage batches 0 and 1
    STAGE_K(0, 0);
    STAGE_V(0, 0);
    if (nt > 1) { STAGE_K(1, 1); STAGE_V(1, 1); }

    for (int kb = 0; kb < nt; ++kb) {
      const int cur = kb & 1;
      if (kb + 1 < nt) asm volatile("s_waitcnt vmcnt(8)" ::: "memory");
      else             asm volatile("s_waitcnt vmcnt(0)" ::: "memory");
      __builtin_amdgcn_s_barrier();
      __builtin_amdgcn_sched_barrier(0);

      // ---- S^T = K_half Q^T  (rows k of this wave's 32-half, cols q)
      f32x16 s;
#pragma unroll
      for (int i = 0; i < 16; ++i) s[i] = 0.f;
      const int kbase = (32 * hi2 + l31) * 128;
      const int ksw = l31 & 7;
      __builtin_amdgcn_s_setprio(1);
#pragma unroll
      for (int st = 0; st < 8; ++st) {
        bf16x8 ka = *(const bf16x8*)&Ks[cur][kbase + (((2 * st + hi) ^ ksw) << 3)];
        s = MFMA32(ka, qf[st], s);
      }
      __builtin_amdgcn_s_setprio(0);

      // ---- mask (diag only), max3-tree LOCAL row max (no cross-half shfl)
      const bool nomask = (kb < qt64) || (hi2 == 0 && qg == 1);
      if (!nomask) {
#pragma unroll
        for (int i = 0; i < 16; ++i) {
          const int kr = kb * 64 + 32 * hi2 + (i & 3) + 8 * (i >> 2) + 4 * hi;
          s[i] = (kr <= qrow) ? s[i] : -INFINITY;
        }
      }
      float a0 = fmax3(s[0], s[1], s[2]);
      float a1 = fmax3(s[3], s[4], s[5]);
      float a2 = fmax3(s[6], s[7], s[8]);
      float a3 = fmax3(s[9], s[10], s[11]);
      float a4 = fmax3(s[12], s[13], s[14]);
      float b0 = fmax3(a0, a1, s[15]);
      float b1 = fmax3(a2, a3, a4);
      float pm = fmaxf(b0, b1);
      // ---- defer-max rescale; __all spans all 64 lanes, so the local max
      // test is equivalent to the full-row max test. Shuffle only if firing.
      if (!__all(pm <= m2 + 8.f)) {
        const float pmf = fmaxf(pm, __shfl_xor(pm, 32));
        const float m2n = fmaxf(m2, pmf);
        const float fc = exp2f(m2 - m2n);
        m2 = m2n; l *= fc;
#pragma unroll
        for (int dt = 0; dt < 4; ++dt)
#pragma unroll
          for (int i = 0; i < 16; ++i) o[dt][i] *= fc;
      }
      // ---- P = exp2(z - m2), tree local sum (cross-hi deferred)
#pragma unroll
      for (int i = 0; i < 16; ++i) s[i] = exp2f(s[i] - m2);
      float t8[8];
#pragma unroll
      for (int i = 0; i < 8; ++i) t8[i] = s[i] + s[i + 8];
#pragma unroll
      for (int i = 0; i < 4; ++i) t8[i] = t8[i] + t8[i + 4];
      l += (t8[0] + t8[1]) + (t8[2] + t8[3]);
      // ---- P C-regs -> B-operand directly (sigma order, perm pack)
      union PB { u32 wd[4]; bf16x8 v; } p0u, p1u;
#pragma unroll
      for (int q_ = 0; q_ < 4; ++q_) {
        p0u.wd[q_] = pk2(s[2 * q_],     s[2 * q_ + 1]);
        p1u.wd[q_] = pk2(s[8 + 2 * q_], s[8 + 2 * q_ + 1]);
      }
      // ---- O^T += V^T_half P_half  (rows d, cols q)
      __builtin_amdgcn_s_setprio(1);
#pragma unroll
      for (int dt = 0; dt < 4; ++dt) {
        const int vrow = (dt * 32 + l31) * 64;
        const int dsw = l31 & 7;
        bf16x8 va0 = *(const bf16x8*)&Vt[cur][vrow + (((4 * hi2 + hi) ^ dsw) << 3)];
        o[dt] = MFMA32(va0, p0u.v, o[dt]);
        bf16x8 va1 = *(const bf16x8*)&Vt[cur][vrow + (((4 * hi2 + 2 + hi) ^ dsw) << 3)];
        o[dt] = MFMA32(va1, p1u.v, o[dt]);
      }
      __builtin_amdgcn_s_setprio(0);

      __builtin_amdgcn_s_barrier();          // all waves done reading buf[cur]
      if (kb + 2 < nt) { STAGE_K(kb + 2, cur); STAGE_V(kb + 2, cur); }
    }

    // ---- in-block merge of the two k-halves (per q-group)
    __syncthreads();                 // all compute done; Ks/Vt reusable
    const float l_tot = l + __shfl_xor(l, 32);
    float* Mrg = (float*)&Ks[0][0];
    float* Mlb = (float*)&Vt[0][0];
    const int sw8 = l31 & 7;
    if (hi2) {
#pragma unroll
      for (int dt = 0; dt < 4; ++dt) {
        const int rbase = ((qg * 4 + dt) * 32 + l31) * 32;
#pragma unroll
        for (int m_ = 0; m_ < 4; ++m_) {
          f32x4 cv;
          cv[0] = o[dt][4 * m_ + 0]; cv[1] = o[dt][4 * m_ + 1];
          cv[2] = o[dt][4 * m_ + 2]; cv[3] = o[dt][4 * m_ + 3];
          *(f32x4*)&Mrg[rbase + (((hi * 4 + m_) ^ sw8) << 2)] = cv;
        }
      }
      if (hi == 0) {
        Mlb[qg * 64 + l31] = m2;
        Mlb[qg * 64 + 32 + l31] = l_tot;
      }
    }
    __syncthreads();
    if (!hi2) {
      const float m1 = Mlb[qg * 64 + l31];
      const float l1 = Mlb[qg * 64 + 32 + l31];
      const float ms = fmaxf(m2, m1);
      const float w0 = exp2f(m2 - ms), w1 = exp2f(m1 - ms);
      const float inv = 1.f / (w0 * l_tot + w1 * l1);
      const float aw0 = w0 * inv, aw1 = w1 * inv;
      const size_t orow = (size_t)(b * 2048 + qrow) * 2048 + h * 128;
#pragma unroll
      for (int dt = 0; dt < 4; ++dt) {
        const int rbase = ((qg * 4 + dt) * 32 + l31) * 32;
#pragma unroll
        for (int m_ = 0; m_ < 4; ++m_) {
          f32x4 o1v = *(const f32x4*)&Mrg[rbase + (((hi * 4 + m_) ^ sw8) << 2)];
          u64 val = 0;
#pragma unroll
          for (int r = 0; r < 4; ++r) {
            __hip_bfloat16 hb =
                __float2bfloat16(aw0 * o[dt][4 * m_ + r] + aw1 * o1v[r]);
            val |= (u64)(*(u16*)&hb) << (16 * r);
          }
          *(u64*)&ao[orow + dt * 32 + 8 * m_ + 4 * hi] = val;
        }
      }
    }
    __syncthreads();                 // protect Mrg/Mlb before next-phase staging
  }
#undef STAGE_K
#undef STAGE_V
}

// ---------------------------------------------------------------- launch
extern "C" void kernel_launch(void* const* d_in, const int* in_sizes, int n_in,
                              void* d_out, int out_size, void* d_ws, size_t ws_size,
                              hipStream_t stream) {
  const float* x  = (const float*)d_in[0];
  const float* wq = (const float*)d_in[2];
  const float* wk = (const float*)d_in[3];
  const float* wv = (const float*)d_in[4];
  const float* wo = (const float*)d_in[5];
  float* out = (float*)d_out;

  u16* xb   = (u16*)d_ws;                       // x bf16   [4096][2048]
  u16* wqkv = xb + (size_t)8388608;             // W bf16   [3072][2048]
  u16* qkv  = wqkv + (size_t)6291456;           // qkv      [4096][3072]
  u16* vtg  = qkv + (size_t)12582912;           // V^T      [8][128][2048]
  u16* wob  = vtg + (size_t)2097152;            // wo bf16  [2048][2048]
  u16* ao   = xb;                               // attn out [4096][2048] (reuse xb)

  cast_all<<<18432, 256, 0, stream>>>(x, wq, wk, wv, wo, xb, wqkv, wob);

  gemm_sm<u16><<<dim3(24, 32), 256, 0, stream>>>(xb, wqkv, qkv, 4096, 3072, 2048);

  rope_vtrans<<<20736, 256, 0, stream>>>(qkv, vtg);

  attn_kernel<<<512, 256, 0, stream>>>(qkv, vtg, ao);

  gemm_sm<float><<<dim3(16, 32), 256, 0, stream>>>(ao, wob, out, 4096, 2048, 2048);
}

// Round 20
// 200.144 us; speedup vs baseline: 1.0375x; 1.0011x over previous
//
#include <hip/hip_runtime.h>
#include <hip/hip_bf16.h>

typedef unsigned short u16;
typedef unsigned int   u32;
typedef unsigned long long u64;
typedef __attribute__((ext_vector_type(8))) short bf16x8;
typedef __attribute__((ext_vector_type(4))) float f32x4;
typedef __attribute__((ext_vector_type(16))) float f32x16;

#define MFMA16(a,b,c) __builtin_amdgcn_mfma_f32_16x16x32_bf16((a),(b),(c),0,0,0)
#define MFMA32(a,b,c) __builtin_amdgcn_mfma_f32_32x32x16_bf16((a),(b),(c),0,0,0)

#define GLD16(gp, lp) __builtin_amdgcn_global_load_lds( \
    (const __attribute__((address_space(1))) void*)(gp), \
    (__attribute__((address_space(3))) void*)(lp), 16, 0, 0)

__device__ inline u32 pkbf(float a, float b) {
  __hip_bfloat16 ha = __float2bfloat16(a), hb = __float2bfloat16(b);
  return (u32)(*(u16*)&ha) | ((u32)(*(u16*)&hb) << 16);
}
__device__ inline float b2f(u16 x) {
  __hip_bfloat16 h; *(u16*)&h = x; return __bfloat162float(h);
}
// fast bf16 pair pack: round (+0x8000) then byte-perm the two high halves
__device__ inline u32 pk2(float a, float b) {
  u32 ua = __builtin_bit_cast(u32, a) + 0x8000u;
  u32 ub = __builtin_bit_cast(u32, b) + 0x8000u;
  return __builtin_amdgcn_perm(ub, ua, 0x07060302u);
}
__device__ inline float fmax3(float a, float b, float c) {
  return fmaxf(fmaxf(a, b), c);
}

// ---------------------------------------------------------------- fused casts
__global__ __launch_bounds__(256) void cast_all(const float* __restrict__ x,
                                                const float* __restrict__ wq,
                                                const float* __restrict__ wk,
                                                const float* __restrict__ wv,
                                                const float* __restrict__ wo,
                                                u16* __restrict__ xb,
                                                u16* __restrict__ wqkv,
                                                u16* __restrict__ wob) {
  int i = blockIdx.x * 256 + threadIdx.x;
  const float* src; u16* dst; int off;
  if (i < 2097152)      { src = x;  dst = xb;                 off = 0; }
  else if (i < 3145728) { src = wq; dst = wqkv;               off = 2097152; }
  else if (i < 3407872) { src = wk; dst = wqkv + 4194304;     off = 3145728; }
  else if (i < 3670016) { src = wv; dst = wqkv + 5242880;     off = 3407872; }
  else                  { src = wo; dst = wob;                off = 3670016; }
  const int k = i - off;
  float4 v = reinterpret_cast<const float4*>(src)[k];
  uint2 pk; pk.x = pkbf(v.x, v.y); pk.y = pkbf(v.z, v.w);
  reinterpret_cast<uint2*>(dst)[k] = pk;
}

__device__ inline void cstore(u16* C, size_t i, float v) {
  __hip_bfloat16 h = __float2bfloat16(v); C[i] = *(u16*)&h;
}
__device__ inline void cstore(float* C, size_t i, float v) { C[i] = v; }

// ---------------------------------------------------------------- GEMM 128x128
// C = A * B^T. 256 thr = 4 waves (2M x 2N). TRIPLE-buffered LDS (48K, still
// 3 blocks/CU): batch j+1 AND j+2 stay in flight across barriers (vmcnt(8)),
// giving loads ~2 iterations of latency cover. Tail: vmcnt(4) at j=nk-2,
// vmcnt(0) at j=nk-1 (at 8 outstanding a vmcnt(8) would be a no-op).
// 0-conflict chunk swizzle; high blocks/CU per r11/r13/r16 evidence.
template<typename OutT>
__global__ __launch_bounds__(256, 4) void gemm_sm(const u16* __restrict__ A,
                                                  const u16* __restrict__ B,
                                                  OutT* __restrict__ C,
                                                  int M, int N, int K) {
  __shared__ u16 As[3][128 * 32];   // 24K
  __shared__ u16 Bs[3][128 * 32];   // 24K

  const int t = threadIdx.x;
  const int lane = t & 63, wid = t >> 6;
  const int l15 = lane & 15, l4 = lane >> 4;
  const int wr = wid >> 1, wc = wid & 1;

  const int nwg = gridDim.x * gridDim.y;
  int lid = blockIdx.y * gridDim.x + blockIdx.x;
  lid = (lid & 7) * (nwg >> 3) + (lid >> 3);
  const int m0 = (lid / gridDim.x) * 128, n0 = (lid % gridDim.x) * 128;

  const int ra0 = t >> 2,         ca0 = (t & 3) ^ ((ra0 >> 1) & 3);
  const int ra1 = (t + 256) >> 2, ca1 = (t & 3) ^ ((ra1 >> 1) & 3);
  const u16* Ag0 = A + (size_t)(m0 + ra0) * K + ca0 * 8;
  const u16* Ag1 = A + (size_t)(m0 + ra1) * K + ca1 * 8;
  const u16* Bg0 = B + (size_t)(n0 + ra0) * K + ca0 * 8;
  const u16* Bg1 = B + (size_t)(n0 + ra1) * K + ca1 * 8;

#define STAGE(k0_, buf_) do {                                                 \
    GLD16(Ag0 + (k0_), &As[buf_][t * 8]);                                     \
    GLD16(Ag1 + (k0_), &As[buf_][2048 + t * 8]);                              \
    GLD16(Bg0 + (k0_), &Bs[buf_][t * 8]);                                     \
    GLD16(Bg1 + (k0_), &Bs[buf_][2048 + t * 8]);                              \
  } while (0)

  const int nk = K >> 5;
  const int ks = (l15 >> 1) & 3;
  const int coff = ((l4 ^ ks) << 3);

  f32x4 acc[4][4] = {};

  STAGE(0, 0);
  if (nk > 1) STAGE(32, 1);
  if (nk > 2) STAGE(64, 2);

  int cur = 0;
  for (int j = 0; j < nk; ++j) {
    if (j + 2 < nk)      asm volatile("s_waitcnt vmcnt(8)" ::: "memory");
    else if (j + 1 < nk) asm volatile("s_waitcnt vmcnt(4)" ::: "memory");
    else                 asm volatile("s_waitcnt vmcnt(0)" ::: "memory");
    __builtin_amdgcn_s_barrier();
    __builtin_amdgcn_sched_barrier(0);

    bf16x8 af[4], bfr[4];
#pragma unroll
    for (int mi = 0; mi < 4; ++mi)
      af[mi] = *(const bf16x8*)&As[cur][(wr * 64 + mi * 16 + l15) * 32 + coff];
#pragma unroll
    for (int ni = 0; ni < 4; ++ni)
      bfr[ni] = *(const bf16x8*)&Bs[cur][(wc * 64 + ni * 16 + l15) * 32 + coff];
    __builtin_amdgcn_s_setprio(1);
#pragma unroll
    for (int mi = 0; mi < 4; ++mi)
#pragma unroll
      for (int ni = 0; ni < 4; ++ni)
        acc[mi][ni] = MFMA16(af[mi], bfr[ni], acc[mi][ni]);
    __builtin_amdgcn_s_setprio(0);

    __builtin_amdgcn_s_barrier();
    if (j + 3 < nk) STAGE((j + 3) << 5, cur);
    cur = (cur == 2) ? 0 : cur + 1;
  }

  const int crow = m0 + wr * 64 + (l4 << 2);
  const int ccol = n0 + wc * 64 + l15;
#pragma unroll
  for (int mi = 0; mi < 4; ++mi)
#pragma unroll
    for (int ni = 0; ni < 4; ++ni)
#pragma unroll
      for (int r = 0; r < 4; ++r)
        cstore(C, (size_t)(crow + mi * 16 + r) * N + (ccol + ni * 16), acc[mi][ni][r]);
#undef STAGE
}

// ---------------------------------------------------------------- RMSNorm+RoPE | Vtrans
// Merged launch: blocks [0,20480) do rmsrope (qkv cols < 2560); blocks
// [20480, 20736) do the V transpose (reads cols >= 2560) -> independent.
__global__ __launch_bounds__(256) void rope_vtrans(u16* __restrict__ qkv,
                                                   u16* __restrict__ vt) {
  __shared__ u16 Ls[64 * 130];
  const int bid = blockIdx.x;
  const int t = threadIdx.x;
  if (bid < 20480) {
    const int lane = t & 63;
    const int gw = bid * 4 + (t >> 6);
    const int row = gw / 20;
    const int hd = gw - row * 20;
    const int col = (hd < 16) ? hd * 128 : 2048 + (hd - 16) * 128;
    const size_t base = (size_t)row * 3072 + col;
    float x1 = b2f(qkv[base + lane]);
    float x2 = b2f(qkv[base + 64 + lane]);
    float ss = x1 * x1 + x2 * x2;
#pragma unroll
    for (int off = 32; off >= 1; off >>= 1) ss += __shfl_xor(ss, off, 64);
    const float qsc = (hd < 16) ? (0.08838834764831845f * 1.44269504088896340f)
                                : 1.0f;
    const float sc = rsqrtf(ss * (1.0f / 128.0f) + 1e-6f) * qsc;
    const int pos = row & 2047;
    const float inv_freq = exp2f(-(float)lane * (13.287712379549449f / 64.0f));
    float sn, cs;
    sincosf((float)pos * inv_freq, &sn, &cs);
    const float a = x1 * sc, b2 = x2 * sc;
    __hip_bfloat16 o1 = __float2bfloat16(a * cs - b2 * sn);
    __hip_bfloat16 o2 = __float2bfloat16(a * sn + b2 * cs);
    qkv[base + lane] = *(u16*)&o1;
    qkv[base + 64 + lane] = *(u16*)&o2;
  } else {
    const int vb = bid - 20480;
    const int g = vb & 7, sb = vb >> 3;
    const int b = g >> 2, kvh = g & 3;
    const int vcol = 2560 + kvh * 128;
    {
      const int row = t >> 4, dch = t & 15;
      const u16* src = qkv + (size_t)(b * 2048 + sb * 64 + row) * 3072 + vcol + dch * 8;
#pragma unroll
      for (int it = 0; it < 4; ++it) {
        bf16x8 v = *(const bf16x8*)(src + (size_t)it * 16 * 3072);
        *(bf16x8*)&Ls[(row + it * 16) * 130 + dch * 8] = v;
      }
    }
    __syncthreads();
    const int c = t & 7, d0 = t >> 3;
    const int k0 = 4 * (8 * (c >> 2) + 4 * ((c >> 1) & 1) + (c & 1));
#pragma unroll
    for (int it = 0; it < 4; ++it) {
      const int d = d0 + 32 * it;
      u16 v[8];
#pragma unroll
      for (int e = 0; e < 8; ++e)
        v[e] = Ls[(k0 + (e & 3) + 8 * (e >> 2)) * 130 + d];
      u64 lo = (u64)v[0] | ((u64)v[1] << 16) | ((u64)v[2] << 32) | ((u64)v[3] << 48);
      u64 hi = (u64)v[4] | ((u64)v[5] << 16) | ((u64)v[6] << 32) | ((u64)v[7] << 48);
      u64* dst = (u64*)(vt + ((size_t)g * 128 + d) * 2048 + sb * 64 + c * 8);
      dst[0] = lo; dst[1] = hi;
    }
  }
}

// ---------------------------------------------------------------- flash attention
// r19 version (best): deferred cross-half max; 512 blocks x 256 thr = 4
// waves (2 qg x 2 k-halves); q64-tile pair (j, 31-j) sequential (33 iters);
// counted vmcnt(8) pipeline, 2 barriers/iter; zero-shuffle PV via
// sigma-ordered vt; XOR bank swizzles; defer-max; exp2-domain Q prescale.
__global__ __launch_bounds__(256, 2) void attn_kernel(const u16* __restrict__ qkv,
                                                      const u16* __restrict__ vt,
                                                      u16* __restrict__ ao) {
  __shared__ u16 Ks[2][64 * 128];   // [k][d], 16B chunks XORed by k&7 (32K)
  __shared__ u16 Vt[2][128 * 64];   // [d][sigma(k)], chunks XORed by d&7 (32K)

  const int t = threadIdx.x;
  const int lane = t & 63, w = t >> 6;
  const int l31 = lane & 31, hi = lane >> 5;
  const int qg = w >> 1, hi2 = w & 1;

  const int bid = blockIdx.x;
  const int g = bid & 7;                  // XCD group = (b, kvh)
  const int b = g >> 2, kvh = g & 3;
  const int idx = bid >> 3;
  const int h = kvh * 4 + (idx & 3);
  const int j = idx >> 2;                 // 0..15 -> pair (j, 31-j)

  const int kcol = 2048 + kvh * 128;
  const u16* vtg = vt + (size_t)g * 128 * 2048;

  const int krow_s = t >> 4, kchk = t & 15;   // K staging (4 GLD/thread)
  const int vd = t >> 3, vc = t & 7;          // V staging (4 GLD/thread)

#define STAGE_K(kb_, buf_) do {                                               \
    const size_t rb_ = (size_t)(b * 2048 + (kb_) * 64);                       \
    _Pragma("unroll")                                                         \
    for (int j_ = 0; j_ < 4; ++j_) {                                          \
      const int row_ = j_ * 16 + krow_s;                                      \
      GLD16(qkv + (rb_ + row_) * 3072 + kcol + ((kchk ^ (row_ & 7)) << 3),    \
            &Ks[buf_][(j_ * 256 + t) << 3]);                                  \
    } } while (0)

#define STAGE_V(kb_, buf_) do {                                               \
    _Pragma("unroll")                                                         \
    for (int j_ = 0; j_ < 4; ++j_) {                                          \
      const int d_ = j_ * 32 + vd;                                            \
      GLD16(vtg + (size_t)d_ * 2048 + (kb_) * 64 + ((vc ^ (d_ & 7)) << 3),    \
            &Vt[buf_][(j_ * 256 + t) << 3]);                                  \
    } } while (0)

  for (int ph = 0; ph < 2; ++ph) {
    const int qt64 = ph ? (31 - j) : j;
    const int q0 = qt64 * 64;
    const int nt = qt64 + 1;
    const int qrow = q0 + 32 * qg + l31;

    // Q fragments (B operand): col=q, k = st*16 + hi*8 + e (pre-scaled)
    bf16x8 qf[8];
    {
      const u16* qp = qkv + (size_t)(b * 2048 + qrow) * 3072 + h * 128 + hi * 8;
#pragma unroll
      for (int st = 0; st < 8; ++st) qf[st] = *(const bf16x8*)(qp + st * 16);
    }

    f32x16 o[4];
#pragma unroll
    for (int dt = 0; dt < 4; ++dt)
#pragma unroll
      for (int i = 0; i < 16; ++i) o[dt][i] = 0.f;
    float m2 = -1e30f, l = 0.f;

    // prologue: stage batches 0 and 1
    STAGE_K(0, 0);
    STAGE_V(0, 0);
    if (nt > 1) { STAGE_K(1, 1); STAGE_V(1, 1); }

    for (int kb = 0; kb < nt; ++kb) {
      const int cur = kb & 1;
      if (kb + 1 < nt) asm volatile("s_waitcnt vmcnt(8)" ::: "memory");
      else             asm volatile("s_waitcnt vmcnt(0)" ::: "memory");
      __builtin_amdgcn_s_barrier();
      __builtin_amdgcn_sched_barrier(0);

      // ---- S^T = K_half Q^T  (rows k of this wave's 32-half, cols q)
      f32x16 s;
#pragma unroll
      for (int i = 0; i < 16; ++i) s[i] = 0.f;
      const int kbase = (32 * hi2 + l31) * 128;
      const int ksw = l31 & 7;
      __builtin_amdgcn_s_setprio(1);
#pragma unroll
      for (int st = 0; st < 8; ++st) {
        bf16x8 ka = *(const bf16x8*)&Ks[cur][kbase + (((2 * st + hi) ^ ksw) << 3)];
        s = MFMA32(ka, qf[st], s);
      }
      __builtin_amdgcn_s_setprio(0);

      // ---- mask (diag only), max3-tree LOCAL row max (no cross-half shfl)
      const bool nomask = (kb < qt64) || (hi2 == 0 && qg == 1);
      if (!nomask) {
#pragma unroll
        for (int i = 0; i < 16; ++i) {
          const int kr = kb * 64 + 32 * hi2 + (i & 3) + 8 * (i >> 2) + 4 * hi;
          s[i] = (kr <= qrow) ? s[i] : -INFINITY;
        }
      }
      float a0 = fmax3(s[0], s[1], s[2]);
      float a1 = fmax3(s[3], s[4], s[5]);
      float a2 = fmax3(s[6], s[7], s[8]);
      float a3 = fmax3(s[9], s[10], s[11]);
      float a4 = fmax3(s[12], s[13], s[14]);
      float b0 = fmax3(a0, a1, s[15]);
      float b1 = fmax3(a2, a3, a4);
      float pm = fmaxf(b0, b1);
      // ---- defer-max rescale; __all spans all 64 lanes -> local test is
      // equivalent to full-row max test; shuffle only inside the rare branch.
      if (!__all(pm <= m2 + 8.f)) {
        const float pmf = fmaxf(pm, __shfl_xor(pm, 32));
        const float m2n = fmaxf(m2, pmf);
        const float fc = exp2f(m2 - m2n);
        m2 = m2n; l *= fc;
#pragma unroll
        for (int dt = 0; dt < 4; ++dt)
#pragma unroll
          for (int i = 0; i < 16; ++i) o[dt][i] *= fc;
      }
      // ---- P = exp2(z - m2), tree local sum (cross-hi deferred)
#pragma unroll
      for (int i = 0; i < 16; ++i) s[i] = exp2f(s[i] - m2);
      float t8[8];
#pragma unroll
      for (int i = 0; i < 8; ++i) t8[i] = s[i] + s[i + 8];
#pragma unroll
      for (int i = 0; i < 4; ++i) t8[i] = t8[i] + t8[i + 4];
      l += (t8[0] + t8[1]) + (t8[2] + t8[3]);
      // ---- P C-regs -> B-operand directly (sigma order, perm pack)
      union PB { u32 wd[4]; bf16x8 v; } p0u, p1u;
#pragma unroll
      for (int q_ = 0; q_ < 4; ++q_) {
        p0u.wd[q_] = pk2(s[2 * q_],     s[2 * q_ + 1]);
        p1u.wd[q_] = pk2(s[8 + 2 * q_], s[8 + 2 * q_ + 1]);
      }
      // ---- O^T += V^T_half P_half  (rows d, cols q)
      __builtin_amdgcn_s_setprio(1);
#pragma unroll
      for (int dt = 0; dt < 4; ++dt) {
        const int vrow = (dt * 32 + l31) * 64;
        const int dsw = l31 & 7;
        bf16x8 va0 = *(const bf16x8*)&Vt[cur][vrow + (((4 * hi2 + hi) ^ dsw) << 3)];
        o[dt] = MFMA32(va0, p0u.v, o[dt]);
        bf16x8 va1 = *(const bf16x8*)&Vt[cur][vrow + (((4 * hi2 + 2 + hi) ^ dsw) << 3)];
        o[dt] = MFMA32(va1, p1u.v, o[dt]);
      }
      __builtin_amdgcn_s_setprio(0);

      __builtin_amdgcn_s_barrier();          // all waves done reading buf[cur]
      if (kb + 2 < nt) { STAGE_K(kb + 2, cur); STAGE_V(kb + 2, cur); }
    }

    // ---- in-block merge of the two k-halves (per q-group)
    __syncthreads();                 // all compute done; Ks/Vt reusable
    const float l_tot = l + __shfl_xor(l, 32);
    float* Mrg = (float*)&Ks[0][0];
    float* Mlb = (float*)&Vt[0][0];
    const int sw8 = l31 & 7;
    if (hi2) {
#pragma unroll
      for (int dt = 0; dt < 4; ++dt) {
        const int rbase = ((qg * 4 + dt) * 32 + l31) * 32;
#pragma unroll
        for (int m_ = 0; m_ < 4; ++m_) {
          f32x4 cv;
          cv[0] = o[dt][4 * m_ + 0]; cv[1] = o[dt][4 * m_ + 1];
          cv[2] = o[dt][4 * m_ + 2]; cv[3] = o[dt][4 * m_ + 3];
          *(f32x4*)&Mrg[rbase + (((hi * 4 + m_) ^ sw8) << 2)] = cv;
        }
      }
      if (hi == 0) {
        Mlb[qg * 64 + l31] = m2;
        Mlb[qg * 64 + 32 + l31] = l_tot;
      }
    }
    __syncthreads();
    if (!hi2) {
      const float m1 = Mlb[qg * 64 + l31];
      const float l1 = Mlb[qg * 64 + 32 + l31];
      const float ms = fmaxf(m2, m1);
      const float w0 = exp2f(m2 - ms), w1 = exp2f(m1 - ms);
      const float inv = 1.f / (w0 * l_tot + w1 * l1);
      const float aw0 = w0 * inv, aw1 = w1 * inv;
      const size_t orow = (size_t)(b * 2048 + qrow) * 2048 + h * 128;
#pragma unroll
      for (int dt = 0; dt < 4; ++dt) {
        const int rbase = ((qg * 4 + dt) * 32 + l31) * 32;
#pragma unroll
        for (int m_ = 0; m_ < 4; ++m_) {
          f32x4 o1v = *(const f32x4*)&Mrg[rbase + (((hi * 4 + m_) ^ sw8) << 2)];
          u64 val = 0;
#pragma unroll
          for (int r = 0; r < 4; ++r) {
            __hip_bfloat16 hb =
                __float2bfloat16(aw0 * o[dt][4 * m_ + r] + aw1 * o1v[r]);
            val |= (u64)(*(u16*)&hb) << (16 * r);
          }
          *(u64*)&ao[orow + dt * 32 + 8 * m_ + 4 * hi] = val;
        }
      }
    }
    __syncthreads();                 // protect Mrg/Mlb before next-phase staging
  }
#undef STAGE_K
#undef STAGE_V
}

// ---------------------------------------------------------------- launch
extern "C" void kernel_launch(void* const* d_in, const int* in_sizes, int n_in,
                              void* d_out, int out_size, void* d_ws, size_t ws_size,
                              hipStream_t stream) {
  const float* x  = (const float*)d_in[0];
  const float* wq = (const float*)d_in[2];
  const float* wk = (const float*)d_in[3];
  const float* wv = (const float*)d_in[4];
  const float* wo = (const float*)d_in[5];
  float* out = (float*)d_out;

  u16* xb   = (u16*)d_ws;                       // x bf16   [4096][2048]
  u16* wqkv = xb + (size_t)8388608;             // W bf16   [3072][2048]
  u16* qkv  = wqkv + (size_t)6291456;           // qkv      [4096][3072]
  u16* vtg  = qkv + (size_t)12582912;           // V^T      [8][128][2048]
  u16* wob  = vtg + (size_t)2097152;            // wo bf16  [2048][2048]
  u16* ao   = xb;                               // attn out [4096][2048] (reuse xb)

  cast_all<<<18432, 256, 0, stream>>>(x, wq, wk, wv, wo, xb, wqkv, wob);

  gemm_sm<u16><<<dim3(24, 32), 256, 0, stream>>>(xb, wqkv, qkv, 4096, 3072, 2048);

  rope_vtrans<<<20736, 256, 0, stream>>>(qkv, vtg);

  attn_kernel<<<512, 256, 0, stream>>>(qkv, vtg, ao);

  gemm_sm<float><<<dim3(16, 32), 256, 0, stream>>>(ao, wob, out, 4096, 2048, 2048);
}

// Round 21
// 193.747 us; speedup vs baseline: 1.0718x; 1.0330x over previous
//
#include <hip/hip_runtime.h>
#include <hip/hip_bf16.h>

typedef unsigned short u16;
typedef unsigned int   u32;
typedef unsigned long long u64;
typedef __attribute__((ext_vector_type(8))) short bf16x8;
typedef __attribute__((ext_vector_type(4))) float f32x4;
typedef __attribute__((ext_vector_type(16))) float f32x16;

#define MFMA16(a,b,c) __builtin_amdgcn_mfma_f32_16x16x32_bf16((a),(b),(c),0,0,0)
#define MFMA32(a,b,c) __builtin_amdgcn_mfma_f32_32x32x16_bf16((a),(b),(c),0,0,0)

#define GLD16(gp, lp) __builtin_amdgcn_global_load_lds( \
    (const __attribute__((address_space(1))) void*)(gp), \
    (__attribute__((address_space(3))) void*)(lp), 16, 0, 0)

__device__ inline u32 pkbf(float a, float b) {
  __hip_bfloat16 ha = __float2bfloat16(a), hb = __float2bfloat16(b);
  return (u32)(*(u16*)&ha) | ((u32)(*(u16*)&hb) << 16);
}
__device__ inline float b2f(u16 x) {
  __hip_bfloat16 h; *(u16*)&h = x; return __bfloat162float(h);
}
// fast bf16 pair pack: round (+0x8000) then byte-perm the two high halves
__device__ inline u32 pk2(float a, float b) {
  u32 ua = __builtin_bit_cast(u32, a) + 0x8000u;
  u32 ub = __builtin_bit_cast(u32, b) + 0x8000u;
  return __builtin_amdgcn_perm(ub, ua, 0x07060302u);
}
__device__ inline float fmax3(float a, float b, float c) {
  return fmaxf(fmaxf(a, b), c);
}

// ---------------------------------------------------------------- fused casts
__global__ __launch_bounds__(256) void cast_all(const float* __restrict__ x,
                                                const float* __restrict__ wq,
                                                const float* __restrict__ wk,
                                                const float* __restrict__ wv,
                                                const float* __restrict__ wo,
                                                u16* __restrict__ xb,
                                                u16* __restrict__ wqkv,
                                                u16* __restrict__ wob) {
  int i = blockIdx.x * 256 + threadIdx.x;
  const float* src; u16* dst; int off;
  if (i < 2097152)      { src = x;  dst = xb;                 off = 0; }
  else if (i < 3145728) { src = wq; dst = wqkv;               off = 2097152; }
  else if (i < 3407872) { src = wk; dst = wqkv + 4194304;     off = 3145728; }
  else if (i < 3670016) { src = wv; dst = wqkv + 5242880;     off = 3407872; }
  else                  { src = wo; dst = wob;                off = 3670016; }
  const int k = i - off;
  float4 v = reinterpret_cast<const float4*>(src)[k];
  uint2 pk; pk.x = pkbf(v.x, v.y); pk.y = pkbf(v.z, v.w);
  reinterpret_cast<uint2*>(dst)[k] = pk;
}

__device__ inline void cstore(u16* C, size_t i, float v) {
  __hip_bfloat16 h = __float2bfloat16(v); C[i] = *(u16*)&h;
}
__device__ inline void cstore(float* C, size_t i, float v) { C[i] = v; }

// ---------------------------------------------------------------- GEMM 256x256 BK=64
// C = A * B^T. 512 thr = 8 waves (2M x 4N), per-wave 128x64 (acc[8][4]).
// 128 KiB LDS dbuf; per buffer 4 regions (u16): A-ks0 [0,8K) | A-ks1 [8K,16K)
// | B-ks0 [16K,24K) | B-ks1 [24K,32K). Each region: 256 rows x 32 u16,
// slot-linear (slot=4*row+q -> slot*16B), source pre-swizzled with the
// PROVEN 2-way-free key q_log = q_phys ^ ((row>>1)&3) (row stride 64B).
// Schedule per K-tile x: 4 phases of 16 MFMA; stage one unit of tile x+1
// per phase in consumption order (A0,B0,A1,B1); TWO counted vmcnt(4)
// checkpoints (before P0 and P2) + 2 barriers per 64-MFMA tile; never a
// full drain mid-loop. FIFO audit: at P0, queue=[A0x,B0x,A1x,B1x](8) ->
// vmcnt(4) confirms A0x,B0x; at P2, queue=[A1x,B1x,A0x+1,B0x+1](8) ->
// vmcnt(4) confirms A1x,B1x. Write-hazard: each region re-staged >=1 full
// barrier after its last readers' lgkmcnt(0).
template<typename OutT>
__global__ __launch_bounds__(512, 2) void gemm_k64(const u16* __restrict__ A,
                                                   const u16* __restrict__ B,
                                                   OutT* __restrict__ C,
                                                   int M, int N, int K) {
  __shared__ u16 SM[65536];   // 128 KiB

  const int t = threadIdx.x;
  const int lane = t & 63, wid = t >> 6;
  const int l15 = lane & 15, l4 = lane >> 4;
  const int wr = wid >> 2, wc = wid & 3;

  const int nwg = gridDim.x * gridDim.y;     // % 8 == 0
  int lid = blockIdx.y * gridDim.x + blockIdx.x;
  lid = (lid & 7) * (nwg >> 3) + (lid >> 3);
  const int m0 = (lid / gridDim.x) * 256, n0 = (lid % gridDim.x) * 256;

  // staging: slot s in {t, t+512}; row = s>>2, q_phys = s&3,
  // logical chunk = q_phys ^ ((row>>1)&3); global kcol = x*64 + ks*32 + lq*8
  const int r0 = t >> 2, q0p = t & 3;
  const int lq0 = q0p ^ ((r0 >> 1) & 3);
  const int r1 = r0 + 128;
  const int lq1 = q0p ^ ((r1 >> 1) & 3);
  const u16* Ap0 = A + (size_t)(m0 + r0) * K + lq0 * 8;
  const u16* Ap1 = A + (size_t)(m0 + r1) * K + lq1 * 8;
  const u16* Bp0 = B + (size_t)(n0 + r0) * K + lq0 * 8;
  const u16* Bp1 = B + (size_t)(n0 + r1) * K + lq1 * 8;

#define STG_A(x_, ks_) do {                                                   \
    const int bb_ = (((x_) & 1) << 15) + ((ks_) << 13);                       \
    GLD16(Ap0 + (x_) * 64 + (ks_) * 32, &SM[bb_ + t * 8]);                    \
    GLD16(Ap1 + (x_) * 64 + (ks_) * 32, &SM[bb_ + 4096 + t * 8]); } while (0)
#define STG_B(x_, ks_) do {                                                   \
    const int bb_ = (((x_) & 1) << 15) + 16384 + ((ks_) << 13);               \
    GLD16(Bp0 + (x_) * 64 + (ks_) * 32, &SM[bb_ + t * 8]);                    \
    GLD16(Bp1 + (x_) * 64 + (ks_) * 32, &SM[bb_ + 4096 + t * 8]); } while (0)

  // fragment reads: q = l4 ^ ((l15>>1)&3) (2-way free; row stride 64B)
  const int q = l4 ^ ((l15 >> 1) & 3);
  const int arow = wr * 128 + l15;     // + mi*16 (+64 for m-frags 4-7)
  const int brow = wc * 64 + l15;      // + ni*16

  f32x4 acc[8][4] = {};
  const int nk = K >> 6;

  // prologue: tile 0 units in consumption order
  STG_A(0, 0); STG_B(0, 0); STG_A(0, 1); STG_B(0, 1);

  for (int x = 0; x < nk; ++x) {
    const int bufb = (x & 1) << 15;
    const bool pre = (x + 1 < nk);

    // ---- checkpoint: A0x, B0x landed (A1x, B1x stay in flight)
    asm volatile("s_waitcnt vmcnt(4)" ::: "memory");
    __builtin_amdgcn_s_barrier();
    __builtin_amdgcn_sched_barrier(0);

    bf16x8 af[4], bfr[4];
    // ---- P0: ks0, m-frags 0-3 (8 ds_read)
#pragma unroll
    for (int i = 0; i < 4; ++i)
      af[i] = *(const bf16x8*)&SM[bufb + (arow + i * 16) * 32 + q * 8];
#pragma unroll
    for (int i = 0; i < 4; ++i)
      bfr[i] = *(const bf16x8*)&SM[bufb + 16384 + (brow + i * 16) * 32 + q * 8];
    if (pre) STG_A(x + 1, 0);
    asm volatile("s_waitcnt lgkmcnt(0)" ::: "memory");
    __builtin_amdgcn_sched_barrier(0);
    __builtin_amdgcn_s_setprio(1);
#pragma unroll
    for (int mi = 0; mi < 4; ++mi)
#pragma unroll
      for (int ni = 0; ni < 4; ++ni)
        acc[mi][ni] = MFMA16(af[mi], bfr[ni], acc[mi][ni]);
    __builtin_amdgcn_s_setprio(0);

    // ---- P1: ks0, m-frags 4-7 (4 ds_read; bfr reused)
#pragma unroll
    for (int i = 0; i < 4; ++i)
      af[i] = *(const bf16x8*)&SM[bufb + (arow + 64 + i * 16) * 32 + q * 8];
    if (pre) STG_B(x + 1, 0);
    asm volatile("s_waitcnt lgkmcnt(0)" ::: "memory");
    __builtin_amdgcn_sched_barrier(0);
    __builtin_amdgcn_s_setprio(1);
#pragma unroll
    for (int mi = 0; mi < 4; ++mi)
#pragma unroll
      for (int ni = 0; ni < 4; ++ni)
        acc[4 + mi][ni] = MFMA16(af[mi], bfr[ni], acc[4 + mi][ni]);
    __builtin_amdgcn_s_setprio(0);

    // ---- checkpoint: A1x, B1x landed (next tile's A0,B0 stay in flight)
    if (pre) asm volatile("s_waitcnt vmcnt(4)" ::: "memory");
    else     asm volatile("s_waitcnt vmcnt(0)" ::: "memory");
    __builtin_amdgcn_s_barrier();
    __builtin_amdgcn_sched_barrier(0);

    // ---- P2: ks1, m-frags 0-3 (8 ds_read)
#pragma unroll
    for (int i = 0; i < 4; ++i)
      af[i] = *(const bf16x8*)&SM[bufb + 8192 + (arow + i * 16) * 32 + q * 8];
#pragma unroll
    for (int i = 0; i < 4; ++i)
      bfr[i] = *(const bf16x8*)&SM[bufb + 24576 + (brow + i * 16) * 32 + q * 8];
    if (pre) STG_A(x + 1, 1);
    asm volatile("s_waitcnt lgkmcnt(0)" ::: "memory");
    __builtin_amdgcn_sched_barrier(0);
    __builtin_amdgcn_s_setprio(1);
#pragma unroll
    for (int mi = 0; mi < 4; ++mi)
#pragma unroll
      for (int ni = 0; ni < 4; ++ni)
        acc[mi][ni] = MFMA16(af[mi], bfr[ni], acc[mi][ni]);
    __builtin_amdgcn_s_setprio(0);

    // ---- P3: ks1, m-frags 4-7 (4 ds_read)
#pragma unroll
    for (int i = 0; i < 4; ++i)
      af[i] = *(const bf16x8*)&SM[bufb + 8192 + (arow + 64 + i * 16) * 32 + q * 8];
    if (pre) STG_B(x + 1, 1);
    asm volatile("s_waitcnt lgkmcnt(0)" ::: "memory");
    __builtin_amdgcn_sched_barrier(0);
    __builtin_amdgcn_s_setprio(1);
#pragma unroll
    for (int mi = 0; mi < 4; ++mi)
#pragma unroll
      for (int ni = 0; ni < 4; ++ni)
        acc[4 + mi][ni] = MFMA16(af[mi], bfr[ni], acc[4 + mi][ni]);
    __builtin_amdgcn_s_setprio(0);
  }

  const int crow = m0 + wr * 128 + (l4 << 2);
  const int ccol = n0 + wc * 64 + l15;
#pragma unroll
  for (int mi = 0; mi < 8; ++mi)
#pragma unroll
    for (int ni = 0; ni < 4; ++ni)
#pragma unroll
      for (int r = 0; r < 4; ++r)
        cstore(C, (size_t)(crow + mi * 16 + r) * N + (ccol + ni * 16), acc[mi][ni][r]);
#undef STG_A
#undef STG_B
}

// ---------------------------------------------------------------- GEMM 128x128
// Output projection. 256 thr = 4 waves (2M x 2N), triple-buffered LDS,
// counted vmcnt; 0-conflict chunk swizzle (r16-r20 proven).
template<typename OutT>
__global__ __launch_bounds__(256, 4) void gemm_sm(const u16* __restrict__ A,
                                                  const u16* __restrict__ B,
                                                  OutT* __restrict__ C,
                                                  int M, int N, int K) {
  __shared__ u16 As[3][128 * 32];   // 24K
  __shared__ u16 Bs[3][128 * 32];   // 24K

  const int t = threadIdx.x;
  const int lane = t & 63, wid = t >> 6;
  const int l15 = lane & 15, l4 = lane >> 4;
  const int wr = wid >> 1, wc = wid & 1;

  const int nwg = gridDim.x * gridDim.y;
  int lid = blockIdx.y * gridDim.x + blockIdx.x;
  lid = (lid & 7) * (nwg >> 3) + (lid >> 3);
  const int m0 = (lid / gridDim.x) * 128, n0 = (lid % gridDim.x) * 128;

  const int ra0 = t >> 2,         ca0 = (t & 3) ^ ((ra0 >> 1) & 3);
  const int ra1 = (t + 256) >> 2, ca1 = (t & 3) ^ ((ra1 >> 1) & 3);
  const u16* Ag0 = A + (size_t)(m0 + ra0) * K + ca0 * 8;
  const u16* Ag1 = A + (size_t)(m0 + ra1) * K + ca1 * 8;
  const u16* Bg0 = B + (size_t)(n0 + ra0) * K + ca0 * 8;
  const u16* Bg1 = B + (size_t)(n0 + ra1) * K + ca1 * 8;

#define STAGE(k0_, buf_) do {                                                 \
    GLD16(Ag0 + (k0_), &As[buf_][t * 8]);                                     \
    GLD16(Ag1 + (k0_), &As[buf_][2048 + t * 8]);                              \
    GLD16(Bg0 + (k0_), &Bs[buf_][t * 8]);                                     \
    GLD16(Bg1 + (k0_), &Bs[buf_][2048 + t * 8]);                              \
  } while (0)

  const int nk = K >> 5;
  const int ks = (l15 >> 1) & 3;
  const int coff = ((l4 ^ ks) << 3);

  f32x4 acc[4][4] = {};

  STAGE(0, 0);
  if (nk > 1) STAGE(32, 1);
  if (nk > 2) STAGE(64, 2);

  int cur = 0;
  for (int j = 0; j < nk; ++j) {
    if (j + 2 < nk)      asm volatile("s_waitcnt vmcnt(8)" ::: "memory");
    else if (j + 1 < nk) asm volatile("s_waitcnt vmcnt(4)" ::: "memory");
    else                 asm volatile("s_waitcnt vmcnt(0)" ::: "memory");
    __builtin_amdgcn_s_barrier();
    __builtin_amdgcn_sched_barrier(0);

    bf16x8 af[4], bfr[4];
#pragma unroll
    for (int mi = 0; mi < 4; ++mi)
      af[mi] = *(const bf16x8*)&As[cur][(wr * 64 + mi * 16 + l15) * 32 + coff];
#pragma unroll
    for (int ni = 0; ni < 4; ++ni)
      bfr[ni] = *(const bf16x8*)&Bs[cur][(wc * 64 + ni * 16 + l15) * 32 + coff];
    __builtin_amdgcn_s_setprio(1);
#pragma unroll
    for (int mi = 0; mi < 4; ++mi)
#pragma unroll
      for (int ni = 0; ni < 4; ++ni)
        acc[mi][ni] = MFMA16(af[mi], bfr[ni], acc[mi][ni]);
    __builtin_amdgcn_s_setprio(0);

    __builtin_amdgcn_s_barrier();
    if (j + 3 < nk) STAGE((j + 3) << 5, cur);
    cur = (cur == 2) ? 0 : cur + 1;
  }

  const int crow = m0 + wr * 64 + (l4 << 2);
  const int ccol = n0 + wc * 64 + l15;
#pragma unroll
  for (int mi = 0; mi < 4; ++mi)
#pragma unroll
    for (int ni = 0; ni < 4; ++ni)
#pragma unroll
      for (int r = 0; r < 4; ++r)
        cstore(C, (size_t)(crow + mi * 16 + r) * N + (ccol + ni * 16), acc[mi][ni][r]);
#undef STAGE
}

// ---------------------------------------------------------------- RMSNorm+RoPE | Vtrans
// Merged launch: blocks [0,20480) do rmsrope (qkv cols < 2560); blocks
// [20480, 20736) do the V transpose (reads cols >= 2560) -> independent.
__global__ __launch_bounds__(256) void rope_vtrans(u16* __restrict__ qkv,
                                                   u16* __restrict__ vt) {
  __shared__ u16 Ls[64 * 130];
  const int bid = blockIdx.x;
  const int t = threadIdx.x;
  if (bid < 20480) {
    const int lane = t & 63;
    const int gw = bid * 4 + (t >> 6);
    const int row = gw / 20;
    const int hd = gw - row * 20;
    const int col = (hd < 16) ? hd * 128 : 2048 + (hd - 16) * 128;
    const size_t base = (size_t)row * 3072 + col;
    float x1 = b2f(qkv[base + lane]);
    float x2 = b2f(qkv[base + 64 + lane]);
    float ss = x1 * x1 + x2 * x2;
#pragma unroll
    for (int off = 32; off >= 1; off >>= 1) ss += __shfl_xor(ss, off, 64);
    const float qsc = (hd < 16) ? (0.08838834764831845f * 1.44269504088896340f)
                                : 1.0f;
    const float sc = rsqrtf(ss * (1.0f / 128.0f) + 1e-6f) * qsc;
    const int pos = row & 2047;
    const float inv_freq = exp2f(-(float)lane * (13.287712379549449f / 64.0f));
    float sn, cs;
    sincosf((float)pos * inv_freq, &sn, &cs);
    const float a = x1 * sc, b2 = x2 * sc;
    __hip_bfloat16 o1 = __float2bfloat16(a * cs - b2 * sn);
    __hip_bfloat16 o2 = __float2bfloat16(a * sn + b2 * cs);
    qkv[base + lane] = *(u16*)&o1;
    qkv[base + 64 + lane] = *(u16*)&o2;
  } else {
    const int vb = bid - 20480;
    const int g = vb & 7, sb = vb >> 3;
    const int b = g >> 2, kvh = g & 3;
    const int vcol = 2560 + kvh * 128;
    {
      const int row = t >> 4, dch = t & 15;
      const u16* src = qkv + (size_t)(b * 2048 + sb * 64 + row) * 3072 + vcol + dch * 8;
#pragma unroll
      for (int it = 0; it < 4; ++it) {
        bf16x8 v = *(const bf16x8*)(src + (size_t)it * 16 * 3072);
        *(bf16x8*)&Ls[(row + it * 16) * 130 + dch * 8] = v;
      }
    }
    __syncthreads();
    const int c = t & 7, d0 = t >> 3;
    const int k0 = 4 * (8 * (c >> 2) + 4 * ((c >> 1) & 1) + (c & 1));
#pragma unroll
    for (int it = 0; it < 4; ++it) {
      const int d = d0 + 32 * it;
      u16 v[8];
#pragma unroll
      for (int e = 0; e < 8; ++e)
        v[e] = Ls[(k0 + (e & 3) + 8 * (e >> 2)) * 130 + d];
      u64 lo = (u64)v[0] | ((u64)v[1] << 16) | ((u64)v[2] << 32) | ((u64)v[3] << 48);
      u64 hi = (u64)v[4] | ((u64)v[5] << 16) | ((u64)v[6] << 32) | ((u64)v[7] << 48);
      u64* dst = (u64*)(vt + ((size_t)g * 128 + d) * 2048 + sb * 64 + c * 8);
      dst[0] = lo; dst[1] = hi;
    }
  }
}

// ---------------------------------------------------------------- flash attention
// r19 version (best): deferred cross-half max; 512 blocks x 256 thr = 4
// waves (2 qg x 2 k-halves); q64-tile pair (j, 31-j) sequential (33 iters);
// counted vmcnt(8) pipeline, 2 barriers/iter; zero-shuffle PV via
// sigma-ordered vt; XOR bank swizzles; defer-max; exp2-domain Q prescale.
__global__ __launch_bounds__(256, 2) void attn_kernel(const u16* __restrict__ qkv,
                                                      const u16* __restrict__ vt,
                                                      u16* __restrict__ ao) {
  __shared__ u16 Ks[2][64 * 128];   // [k][d], 16B chunks XORed by k&7 (32K)
  __shared__ u16 Vt[2][128 * 64];   // [d][sigma(k)], chunks XORed by d&7 (32K)

  const int t = threadIdx.x;
  const int lane = t & 63, w = t >> 6;
  const int l31 = lane & 31, hi = lane >> 5;
  const int qg = w >> 1, hi2 = w & 1;

  const int bid = blockIdx.x;
  const int g = bid & 7;                  // XCD group = (b, kvh)
  const int b = g >> 2, kvh = g & 3;
  const int idx = bid >> 3;
  const int h = kvh * 4 + (idx & 3);
  const int j = idx >> 2;                 // 0..15 -> pair (j, 31-j)

  const int kcol = 2048 + kvh * 128;
  const u16* vtg = vt + (size_t)g * 128 * 2048;

  const int krow_s = t >> 4, kchk = t & 15;   // K staging (4 GLD/thread)
  const int vd = t >> 3, vc = t & 7;          // V staging (4 GLD/thread)

#define STAGE_K(kb_, buf_) do {                                               \
    const size_t rb_ = (size_t)(b * 2048 + (kb_) * 64);                       \
    _Pragma("unroll")                                                         \
    for (int j_ = 0; j_ < 4; ++j_) {                                          \
      const int row_ = j_ * 16 + krow_s;                                      \
      GLD16(qkv + (rb_ + row_) * 3072 + kcol + ((kchk ^ (row_ & 7)) << 3),    \
            &Ks[buf_][(j_ * 256 + t) << 3]);                                  \
    } } while (0)

#define STAGE_V(kb_, buf_) do {                                               \
    _Pragma("unroll")                                                         \
    for (int j_ = 0; j_ < 4; ++j_) {                                          \
      const int d_ = j_ * 32 + vd;                                            \
      GLD16(vtg + (size_t)d_ * 2048 + (kb_) * 64 + ((vc ^ (d_ & 7)) << 3),    \
            &Vt[buf_][(j_ * 256 + t) << 3]);                                  \
    } } while (0)

  for (int ph = 0; ph < 2; ++ph) {
    const int qt64 = ph ? (31 - j) : j;
    const int q0 = qt64 * 64;
    const int nt = qt64 + 1;
    const int qrow = q0 + 32 * qg + l31;

    // Q fragments (B operand): col=q, k = st*16 + hi*8 + e (pre-scaled)
    bf16x8 qf[8];
    {
      const u16* qp = qkv + (size_t)(b * 2048 + qrow) * 3072 + h * 128 + hi * 8;
#pragma unroll
      for (int st = 0; st < 8; ++st) qf[st] = *(const bf16x8*)(qp + st * 16);
    }

    f32x16 o[4];
#pragma unroll
    for (int dt = 0; dt < 4; ++dt)
#pragma unroll
      for (int i = 0; i < 16; ++i) o[dt][i] = 0.f;
    float m2 = -1e30f, l = 0.f;

    // prologue: stage batches 0 and 1
    STAGE_K(0, 0);
    STAGE_V(0, 0);
    if (nt > 1) { STAGE_K(1, 1); STAGE_V(1, 1); }

    for (int kb = 0; kb < nt; ++kb) {
      const int cur = kb & 1;
      if (kb + 1 < nt) asm volatile("s_waitcnt vmcnt(8)" ::: "memory");
      else             asm volatile("s_waitcnt vmcnt(0)" ::: "memory");
      __builtin_amdgcn_s_barrier();
      __builtin_amdgcn_sched_barrier(0);

      // ---- S^T = K_half Q^T  (rows k of this wave's 32-half, cols q)
      f32x16 s;
#pragma unroll
      for (int i = 0; i < 16; ++i) s[i] = 0.f;
      const int kbase = (32 * hi2 + l31) * 128;
      const int ksw = l31 & 7;
      __builtin_amdgcn_s_setprio(1);
#pragma unroll
      for (int st = 0; st < 8; ++st) {
        bf16x8 ka = *(const bf16x8*)&Ks[cur][kbase + (((2 * st + hi) ^ ksw) << 3)];
        s = MFMA32(ka, qf[st], s);
      }
      __builtin_amdgcn_s_setprio(0);

      // ---- mask (diag only), max3-tree LOCAL row max (no cross-half shfl)
      const bool nomask = (kb < qt64) || (hi2 == 0 && qg == 1);
      if (!nomask) {
#pragma unroll
        for (int i = 0; i < 16; ++i) {
          const int kr = kb * 64 + 32 * hi2 + (i & 3) + 8 * (i >> 2) + 4 * hi;
          s[i] = (kr <= qrow) ? s[i] : -INFINITY;
        }
      }
      float a0 = fmax3(s[0], s[1], s[2]);
      float a1 = fmax3(s[3], s[4], s[5]);
      float a2 = fmax3(s[6], s[7], s[8]);
      float a3 = fmax3(s[9], s[10], s[11]);
      float a4 = fmax3(s[12], s[13], s[14]);
      float b0 = fmax3(a0, a1, s[15]);
      float b1 = fmax3(a2, a3, a4);
      float pm = fmaxf(b0, b1);
      // ---- defer-max rescale; __all spans all 64 lanes -> local test is
      // equivalent to full-row max test; shuffle only inside the rare branch.
      if (!__all(pm <= m2 + 8.f)) {
        const float pmf = fmaxf(pm, __shfl_xor(pm, 32));
        const float m2n = fmaxf(m2, pmf);
        const float fc = exp2f(m2 - m2n);
        m2 = m2n; l *= fc;
#pragma unroll
        for (int dt = 0; dt < 4; ++dt)
#pragma unroll
          for (int i = 0; i < 16; ++i) o[dt][i] *= fc;
      }
      // ---- P = exp2(z - m2), tree local sum (cross-hi deferred)
#pragma unroll
      for (int i = 0; i < 16; ++i) s[i] = exp2f(s[i] - m2);
      float t8[8];
#pragma unroll
      for (int i = 0; i < 8; ++i) t8[i] = s[i] + s[i + 8];
#pragma unroll
      for (int i = 0; i < 4; ++i) t8[i] = t8[i] + t8[i + 4];
      l += (t8[0] + t8[1]) + (t8[2] + t8[3]);
      // ---- P C-regs -> B-operand directly (sigma order, perm pack)
      union PB { u32 wd[4]; bf16x8 v; } p0u, p1u;
#pragma unroll
      for (int q_ = 0; q_ < 4; ++q_) {
        p0u.wd[q_] = pk2(s[2 * q_],     s[2 * q_ + 1]);
        p1u.wd[q_] = pk2(s[8 + 2 * q_], s[8 + 2 * q_ + 1]);
      }
      // ---- O^T += V^T_half P_half  (rows d, cols q)
      __builtin_amdgcn_s_setprio(1);
#pragma unroll
      for (int dt = 0; dt < 4; ++dt) {
        const int vrow = (dt * 32 + l31) * 64;
        const int dsw = l31 & 7;
        bf16x8 va0 = *(const bf16x8*)&Vt[cur][vrow + (((4 * hi2 + hi) ^ dsw) << 3)];
        o[dt] = MFMA32(va0, p0u.v, o[dt]);
        bf16x8 va1 = *(const bf16x8*)&Vt[cur][vrow + (((4 * hi2 + 2 + hi) ^ dsw) << 3)];
        o[dt] = MFMA32(va1, p1u.v, o[dt]);
      }
      __builtin_amdgcn_s_setprio(0);

      __builtin_amdgcn_s_barrier();          // all waves done reading buf[cur]
      if (kb + 2 < nt) { STAGE_K(kb + 2, cur); STAGE_V(kb + 2, cur); }
    }

    // ---- in-block merge of the two k-halves (per q-group)
    __syncthreads();                 // all compute done; Ks/Vt reusable
    const float l_tot = l + __shfl_xor(l, 32);
    float* Mrg = (float*)&Ks[0][0];
    float* Mlb = (float*)&Vt[0][0];
    const int sw8 = l31 & 7;
    if (hi2) {
#pragma unroll
      for (int dt = 0; dt < 4; ++dt) {
        const int rbase = ((qg * 4 + dt) * 32 + l31) * 32;
#pragma unroll
        for (int m_ = 0; m_ < 4; ++m_) {
          f32x4 cv;
          cv[0] = o[dt][4 * m_ + 0]; cv[1] = o[dt][4 * m_ + 1];
          cv[2] = o[dt][4 * m_ + 2]; cv[3] = o[dt][4 * m_ + 3];
          *(f32x4*)&Mrg[rbase + (((hi * 4 + m_) ^ sw8) << 2)] = cv;
        }
      }
      if (hi == 0) {
        Mlb[qg * 64 + l31] = m2;
        Mlb[qg * 64 + 32 + l31] = l_tot;
      }
    }
    __syncthreads();
    if (!hi2) {
      const float m1 = Mlb[qg * 64 + l31];
      const float l1 = Mlb[qg * 64 + 32 + l31];
      const float ms = fmaxf(m2, m1);
      const float w0 = exp2f(m2 - ms), w1 = exp2f(m1 - ms);
      const float inv = 1.f / (w0 * l_tot + w1 * l1);
      const float aw0 = w0 * inv, aw1 = w1 * inv;
      const size_t orow = (size_t)(b * 2048 + qrow) * 2048 + h * 128;
#pragma unroll
      for (int dt = 0; dt < 4; ++dt) {
        const int rbase = ((qg * 4 + dt) * 32 + l31) * 32;
#pragma unroll
        for (int m_ = 0; m_ < 4; ++m_) {
          f32x4 o1v = *(const f32x4*)&Mrg[rbase + (((hi * 4 + m_) ^ sw8) << 2)];
          u64 val = 0;
#pragma unroll
          for (int r = 0; r < 4; ++r) {
            __hip_bfloat16 hb =
                __float2bfloat16(aw0 * o[dt][4 * m_ + r] + aw1 * o1v[r]);
            val |= (u64)(*(u16*)&hb) << (16 * r);
          }
          *(u64*)&ao[orow + dt * 32 + 8 * m_ + 4 * hi] = val;
        }
      }
    }
    __syncthreads();                 // protect Mrg/Mlb before next-phase staging
  }
#undef STAGE_K
#undef STAGE_V
}

// ---------------------------------------------------------------- launch
extern "C" void kernel_launch(void* const* d_in, const int* in_sizes, int n_in,
                              void* d_out, int out_size, void* d_ws, size_t ws_size,
                              hipStream_t stream) {
  const float* x  = (const float*)d_in[0];
  const float* wq = (const float*)d_in[2];
  const float* wk = (const float*)d_in[3];
  const float* wv = (const float*)d_in[4];
  const float* wo = (const float*)d_in[5];
  float* out = (float*)d_out;

  u16* xb   = (u16*)d_ws;                       // x bf16   [4096][2048]
  u16* wqkv = xb + (size_t)8388608;             // W bf16   [3072][2048]
  u16* qkv  = wqkv + (size_t)6291456;           // qkv      [4096][3072]
  u16* vtg  = qkv + (size_t)12582912;           // V^T      [8][128][2048]
  u16* wob  = vtg + (size_t)2097152;            // wo bf16  [2048][2048]
  u16* ao   = xb;                               // attn out [4096][2048] (reuse xb)

  cast_all<<<18432, 256, 0, stream>>>(x, wq, wk, wv, wo, xb, wqkv, wob);

  gemm_k64<u16><<<dim3(12, 16), 512, 0, stream>>>(xb, wqkv, qkv, 4096, 3072, 2048);

  rope_vtrans<<<20736, 256, 0, stream>>>(qkv, vtg);

  attn_kernel<<<512, 256, 0, stream>>>(qkv, vtg, ao);

  gemm_sm<float><<<dim3(16, 32), 256, 0, stream>>>(ao, wob, out, 4096, 2048, 2048);
}